// Round 5
// baseline (389.589 us; speedup 1.0000x reference)
//
#include <hip/hip_runtime.h>

#define Bn 4
#define Cn 256
#define C8 32
#define Hn 64
#define Wn 64
#define HWn 4096
#define PADR 80
#define ROWS (HWn + 2 * PADR)   // 4256 padded pixel-rows per batch
#define MARGIN 6e-3f

typedef __bf16 bf16x8 __attribute__((ext_vector_type(8)));
typedef float floatx4 __attribute__((ext_vector_type(4)));
typedef unsigned short u16x8 __attribute__((ext_vector_type(8)));

__device__ __forceinline__ unsigned short f2bf(float f) {
  union { float f; unsigned int u; } c; c.f = f;
  unsigned int u = c.u;
  return (unsigned short)((u + 0x7FFFu + ((u >> 16) & 1u)) >> 16);  // RNE
}
__device__ __forceinline__ float bf2f(unsigned short h) {
  union { unsigned int u; float f; } c; c.u = ((unsigned int)h) << 16;
  return c.f;
}
__device__ __forceinline__ void gl_lds16(const void* g, void* l) {
  __builtin_amdgcn_global_load_lds(
      (__attribute__((address_space(1))) void*)(uintptr_t)g,
      (__attribute__((address_space(3))) void*)(uintptr_t)l, 16, 0, 0);
}

// ---------------------------------------------------------------------------
// K0: weight prep + zero flagged-query counter (unchanged).
// ---------------------------------------------------------------------------
__global__ void prep_w(const float* __restrict__ Wq, const float* __restrict__ Wk,
                       const float* __restrict__ Wv, const float* __restrict__ Wf,
                       float* __restrict__ Wqf, float* __restrict__ Wkf,
                       unsigned short* __restrict__ Wvb, unsigned short* __restrict__ Wfb,
                       int* __restrict__ cnt) {
  size_t t = (size_t)blockIdx.x * 256 + threadIdx.x;
  if (t == 0) cnt[0] = 0;
  if (t < 8192) {
    int o = (int)(t / 256), c = (int)(t % 256);
    Wqf[(size_t)c * 32 + o] = Wq[t];
    Wkf[(size_t)c * 32 + o] = Wk[t];
  }
  if (t < 65536) Wvb[t] = f2bf(Wv[t]);   // [o][c] row-major already
  if (t < (size_t)9 * 256 * 512) {
    int tap = (int)(t / (256 * 512));
    int rem = (int)(t % (256 * 512));
    int o = rem / 512, ci = rem % 512;
    Wfb[t] = f2bf(Wf[((size_t)o * 512 + ci) * 9 + tap]);
  }
}

// ---------------------------------------------------------------------------
// K1: q/k projection in FP32 (unchanged from R9).
// ---------------------------------------------------------------------------
__global__ __launch_bounds__(1024) void proj_qk(
    const float* __restrict__ cross_x, const float* __restrict__ front_x,
    const float* __restrict__ Wqf, const float* __restrict__ bq,
    const float* __restrict__ Wkf, const float* __restrict__ bk,
    float* __restrict__ qf, float* __restrict__ kf,
    unsigned short* __restrict__ qhi, unsigned short* __restrict__ qlo,
    unsigned short* __restrict__ khi, unsigned short* __restrict__ klo) {
  int tid = threadIdx.x;
  int lane = tid & 63, wv = tid >> 6;    // 16 waves
  int slice = wv & 3;                    // o-slice (8 o each)
  int chunk = wv >> 2;                   // c-chunk (64 c each)
  int j = blockIdx.x * 64 + lane;
  int b = blockIdx.y;
  int z = blockIdx.z;
  const float* x = (z == 0) ? cross_x : front_x;
  const float* Wg = (z == 0) ? Wqf : Wkf;
  const float* bd = (z == 0) ? bq : bk;
  float* outp = (z == 0) ? qf : kf;
  unsigned short* hip_ = (z == 0) ? qhi : khi;
  unsigned short* lop_ = (z == 0) ? qlo : klo;
  int o0 = slice * 8;
  int c0 = chunk * 64;

  __shared__ __align__(16) float Wl[8192];        // [c][32] fp32, 32KB
  __shared__ float part[3 * 4 * 8 * 64];          // [chunk-1][slice][o][lane] 24KB

  for (int u = tid; u < 8192; u += 1024) Wl[u] = Wg[u];
  __syncthreads();

  const float* xb = x + (size_t)b * Cn * HWn + j;
  floatx4 a0 = (floatx4)0.0f, a1 = (floatx4)0.0f;
#pragma unroll 16
  for (int c = c0; c < c0 + 64; ++c) {
    float xv = xb[(size_t)c * HWn];
    floatx4 wa = *reinterpret_cast<const floatx4*>(&Wl[c * 32 + o0]);      // broadcast
    floatx4 wb = *reinterpret_cast<const floatx4*>(&Wl[c * 32 + o0 + 4]);
    a0 += wa * xv;
    a1 += wb * xv;
  }
  if (chunk > 0) {
    float* dst = &part[(((chunk - 1) * 4 + slice) * 8) * 64];
#pragma unroll
    for (int o = 0; o < 4; ++o) { dst[o * 64 + lane] = a0[o]; dst[(o + 4) * 64 + lane] = a1[o]; }
  }
  __syncthreads();
  if (chunk != 0) return;
#pragma unroll
  for (int q = 0; q < 3; ++q) {
    const float* src = &part[((q * 4 + slice) * 8) * 64];
#pragma unroll
    for (int o = 0; o < 4; ++o) { a0[o] += src[o * 64 + lane]; a1[o] += src[(o + 4) * 64 + lane]; }
  }
  float acc[8];
#pragma unroll
  for (int o = 0; o < 4; ++o) { acc[o] = a0[o] + bd[o0 + o]; acc[o + 4] = a1[o] + bd[o0 + 4 + o]; }

  float* op = outp + ((size_t)b * HWn + j) * C8 + o0;
  u16x8 hv, lv;
#pragma unroll
  for (int o = 0; o < 8; ++o) {
    op[o] = acc[o];
    unsigned short h = f2bf(acc[o]);
    hv[o] = h;
    lv[o] = f2bf(acc[o] - bf2f(h));
  }
  *reinterpret_cast<u16x8*>(hip_ + ((size_t)b * HWn + j) * C8 + o0) = hv;
  *reinterpret_cast<u16x8*>(lop_ + ((size_t)b * HWn + j) * C8 + o0) = lv;
}

// ---------------------------------------------------------------------------
// K2: approximate energy via split-bf16 MFMA (R10: branchless med3 tracking,
// index packed in mantissa LSBs, 32-query tile for 2 blocks/CU).
// ---------------------------------------------------------------------------
__global__ __launch_bounds__(1024) void energy_approx(
    const unsigned short* __restrict__ khi, const unsigned short* __restrict__ klo,
    const unsigned short* __restrict__ qhi, const unsigned short* __restrict__ qlo,
    float* __restrict__ star, int* __restrict__ argb,
    int* __restrict__ cnt, int* __restrict__ list) {
  int b = blockIdx.y;
  int j0 = blockIdx.x * 32;
  int tid = threadIdx.x;
  int lane = tid & 63, wv = tid >> 6;   // wv 0..15
  int lm = lane & 15, lq = lane >> 4;

  __shared__ float bv1S[16][32];
  __shared__ int   bi1S[16][32];
  __shared__ float bv2S[16][32];

  bf16x8 qh[2], ql[2];
#pragma unroll
  for (int s = 0; s < 2; ++s) {
    int j = j0 + s * 16 + lm;
    qh[s] = *reinterpret_cast<const bf16x8*>(qhi + ((size_t)b * HWn + j) * 32 + lq * 8);
    ql[s] = *reinterpret_cast<const bf16x8*>(qlo + ((size_t)b * HWn + j) * 32 + lq * 8);
  }
  const unsigned short* kh_base = khi + (size_t)b * HWn * 32 + lq * 8;
  const unsigned short* kl_base = klo + (size_t)b * HWn * 32 + lq * 8;

  float b1[2], b2[2];
#pragma unroll
  for (int s = 0; s < 2; ++s) { b1[s] = -3.0e38f; b2[s] = -3.0e38f; }

  int ibase = wv * 256;
#pragma unroll 4
  for (int it = 0; it < 16; ++it) {
    int i0 = ibase + it * 16;
    bf16x8 ah = *reinterpret_cast<const bf16x8*>(kh_base + (size_t)(i0 + lm) * 32);
    bf16x8 al = *reinterpret_cast<const bf16x8*>(kl_base + (size_t)(i0 + lm) * 32);
#pragma unroll
    for (int s = 0; s < 2; ++s) {
      floatx4 acc = (floatx4)0.0f;
      acc = __builtin_amdgcn_mfma_f32_16x16x32_bf16(ah, qh[s], acc, 0, 0, 0);
      acc = __builtin_amdgcn_mfma_f32_16x16x32_bf16(ah, ql[s], acc, 0, 0, 0);
      acc = __builtin_amdgcn_mfma_f32_16x16x32_bf16(al, qh[s], acc, 0, 0, 0);
#pragma unroll
      for (int r = 0; r < 4; ++r) {
        unsigned code = (unsigned)(it * 4 + r);   // SGPR-uniform per (it,r)
        union { float f; unsigned u; } cv; cv.f = acc[r];
        cv.u = (cv.u & ~63u) | code;              // v_and_or_b32
        float vp = cv.f;
        // exact new second-best: median(vp, b1_old, b2_old)
        b2[s] = __builtin_amdgcn_fmed3f(vp, b1[s], b2[s]);
        b1[s] = fmaxf(b1[s], vp);
      }
    }
  }
  int i1[2];
#pragma unroll
  for (int s = 0; s < 2; ++s) {
    union { float f; unsigned u; } cv; cv.f = b1[s];
    unsigned code = cv.u & 63u;                   // (it<<2)|r of the winner
    i1[s] = ibase + (int)(code >> 2) * 16 + lq * 4 + (int)(code & 3u);
  }
#pragma unroll
  for (int s = 0; s < 2; ++s) {
#pragma unroll
    for (int m = 16; m <= 32; m <<= 1) {
      float ob1 = __shfl_xor(b1[s], m, 64);
      int oi1 = __shfl_xor(i1[s], m, 64);
      float ob2 = __shfl_xor(b2[s], m, 64);
      float c2;
      if (ob1 > b1[s] || (ob1 == b1[s] && oi1 < i1[s])) {
        c2 = fmaxf(b1[s], ob2);
        b1[s] = ob1; i1[s] = oi1;
      } else {
        c2 = fmaxf(ob1, b2[s]);
      }
      b2[s] = c2;
    }
    if (lq == 0) {
      bv1S[wv][s * 16 + lm] = b1[s];
      bi1S[wv][s * 16 + lm] = i1[s];
      bv2S[wv][s * 16 + lm] = b2[s];
    }
  }
  __syncthreads();
  if (tid < 32) {
    float B1 = bv1S[0][tid];
    int I1 = bi1S[0][tid];
    float B2 = bv2S[0][tid];
#pragma unroll
    for (int w = 1; w < 16; ++w) {
      float v1 = bv1S[w][tid];
      int ii = bi1S[w][tid];
      float v2 = bv2S[w][tid];
      if (v1 > B1) { B2 = fmaxf(B1, v2); B1 = v1; I1 = ii; }
      else B2 = fmaxf(B2, v1);
    }
    size_t o = (size_t)b * HWn + j0 + tid;
    union { float f; unsigned u; } cs; cs.f = B1;
    cs.u &= ~63u;                                 // strip packed index bits
    star[o] = cs.f;
    argb[o] = I1;
    if (B1 - B2 < MARGIN) {
      int slot = atomicAdd(cnt, 1);
      list[slot] = (b << 12) | (j0 + (int)tid);
    }
  }
}

// ---------------------------------------------------------------------------
// K3: recheck — fp64 accumulation over fp32 q,k (unchanged from R9).
// ---------------------------------------------------------------------------
__global__ __launch_bounds__(256) void recheck(
    const float* __restrict__ qf, const float* __restrict__ kf,
    const int* __restrict__ cnt, const int* __restrict__ list,
    float* __restrict__ star, int* __restrict__ argb) {
  __shared__ double bvS[4];
  __shared__ int biS[4];
  int n = cnt[0];
  int tid = threadIdx.x;
  int lane = tid & 63, wv = tid >> 6;
  for (int idx = blockIdx.x; idx < n; idx += gridDim.x) {
    int e = list[idx];
    int b = e >> 12, j = e & 4095;
    const float* qp = qf + ((size_t)b * HWn + j) * 32;
    double qj[32];
#pragma unroll
    for (int o = 0; o < 32; ++o) qj[o] = (double)qp[o];
    double best = -1.0e300;
    int bi = 1 << 30;
    for (int i = tid; i < HWn; i += 256) {
      const float* kp = kf + ((size_t)b * HWn + i) * 32;
      double s = 0.0;
#pragma unroll
      for (int o = 0; o < 32; ++o) s += (double)kp[o] * qj[o];
      if (s > best) { best = s; bi = i; }
    }
#pragma unroll
    for (int m = 1; m < 64; m <<= 1) {
      double ob = __shfl_xor(best, m, 64);
      int oi = __shfl_xor(bi, m, 64);
      if (ob > best || (ob == best && oi < bi)) { best = ob; bi = oi; }
    }
    if (lane == 0) { bvS[wv] = best; biS[wv] = bi; }
    __syncthreads();
    if (tid == 0) {
#pragma unroll
      for (int w = 1; w < 4; ++w) {
        if (bvS[w] > best || (bvS[w] == best && biS[w] < bi)) {
          best = bvS[w]; bi = biS[w];
        }
      }
      star[(size_t)b * HWn + j] = (float)best;
      argb[(size_t)b * HWn + j] = bi;
    }
    __syncthreads();
  }
}

// ---------------------------------------------------------------------------
// K4: transpose to bf16 pixel-major (unchanged).
// ---------------------------------------------------------------------------
__global__ __launch_bounds__(256) void cat_fx(
    const float* __restrict__ fx, const float* __restrict__ fxh,
    unsigned short* __restrict__ catC, unsigned short* __restrict__ xht) {
  int j0 = blockIdx.x * 64;
  int ci0 = blockIdx.y * 64;
  int b = blockIdx.z >> 1;
  int which = blockIdx.z & 1;
  int tid = threadIdx.x;
  __shared__ unsigned short tile[64][66];

  const float* src = (which == 0) ? fx : fxh;
  for (int u = tid; u < 4096; u += 256) {
    int cl = u >> 6, hw_l = u & 63;
    tile[cl][hw_l] = f2bf(src[((size_t)(b * Cn + ci0 + cl)) * HWn + j0 + hw_l]);
  }
  __syncthreads();
  if (which == 0) {
    for (int u = tid; u < 4096; u += 256) {
      int hw_l = u >> 6, cl = u & 63;
      catC[((size_t)b * ROWS + PADR + j0 + hw_l) * 512 + ci0 + cl] = tile[cl][hw_l];
    }
  } else {
    for (int u = tid; u < 4096; u += 256) {
      int hw_l = u >> 6, cl = u & 63;
      xht[((size_t)b * HWn + j0 + hw_l) * 256 + ci0 + cl] = tile[cl][hw_l];
    }
  }
}

// ---------------------------------------------------------------------------
// K5: v projection as bf16 MFMA GEMM, XOR-swizzled LDS (R13 counted-vmcnt).
// ---------------------------------------------------------------------------
__global__ __launch_bounds__(256) void proj_v_mfma(
    const unsigned short* __restrict__ xht, const unsigned short* __restrict__ Wvb,
    const float* __restrict__ bv, unsigned short* __restrict__ vbf) {
  int m0 = blockIdx.x * 128;
  int o0 = blockIdx.y * 128;
  int b = blockIdx.z;
  int tid = threadIdx.x;
  int lane = tid & 63, wv = tid >> 6;
  int wm = wv >> 1, wn = wv & 1;
  int lm = lane & 15, lq = lane >> 4;

  union SMu {
    struct { unsigned short A[2][128 * 32]; unsigned short B[2][128 * 32]; } st;
    unsigned short TS[128 * 136];
  };
  __shared__ __align__(16) SMu sm;

  floatx4 acc[4][4];
#pragma unroll
  for (int im = 0; im < 4; ++im)
#pragma unroll
    for (int in = 0; in < 4; ++in) acc[im][in] = (floatx4)0.0f;

  const int srow = lane >> 2;
  const int soff = (((lane & 3) ^ ((lane >> 3) & 3)) * 8);   // swizzled source chunk
  const int sa = (lq ^ ((lm >> 1) & 3)) * 8;                 // swizzled read column
  const unsigned short* ag = Wvb + (size_t)o0 * 256;
  const unsigned short* bg = xht + ((size_t)b * HWn + m0) * 256;

  auto STAGE = [&](int buf, int kc) {
#pragma unroll
    for (int i = 0; i < 2; ++i) {
      int r0 = wv * 32 + i * 16;
      gl_lds16(ag + ((size_t)(r0 + srow)) * 256 + kc + soff, &sm.st.A[buf][r0 * 32]);
      gl_lds16(bg + ((size_t)(r0 + srow)) * 256 + kc + soff, &sm.st.B[buf][r0 * 32]);
    }
  };
  auto COMPUTE = [&](int buf) {
    bf16x8 afr[4];
#pragma unroll
    for (int im = 0; im < 4; ++im)
      afr[im] = *reinterpret_cast<const bf16x8*>(
          &sm.st.A[buf][(wm * 64 + im * 16 + lm) * 32 + sa]);
#pragma unroll
    for (int in = 0; in < 4; ++in) {
      bf16x8 bfr = *reinterpret_cast<const bf16x8*>(
          &sm.st.B[buf][(wn * 64 + in * 16 + lm) * 32 + sa]);
#pragma unroll
      for (int im = 0; im < 4; ++im)
        acc[im][in] = __builtin_amdgcn_mfma_f32_16x16x32_bf16(
            afr[im], bfr, acc[im][in], 0, 0, 0);
    }
  };

  STAGE(0, 0);
#pragma unroll 2
  for (int st = 0; st < 8; ++st) {
    __builtin_amdgcn_s_barrier();            // buf[(st+1)&1] free to overwrite
    if (st < 7) {
      STAGE((st + 1) & 1, (st + 1) * 32);
      asm volatile("s_waitcnt vmcnt(4)" ::: "memory");   // tile st landed
    } else {
      asm volatile("s_waitcnt vmcnt(0)" ::: "memory");
    }
    __builtin_amdgcn_s_barrier();
    __builtin_amdgcn_sched_barrier(0);
    COMPUTE(st & 1);
  }
  __builtin_amdgcn_s_barrier();   // all waves done reading before TS overwrite

  // epilogue: TS aliases the (now dead) stage buffers.
#pragma unroll
  for (int in = 0; in < 4; ++in) {
    int pl = wn * 64 + in * 16 + lm;
#pragma unroll
    for (int im = 0; im < 4; ++im) {
#pragma unroll
      for (int r = 0; r < 4; ++r) {
        int ol = wm * 64 + im * 16 + lq * 4 + r;
        sm.TS[pl * 136 + ol] = f2bf(acc[im][in][r] + bv[o0 + ol]);
      }
    }
  }
  __syncthreads();
  for (int idx = tid; idx < 128 * 16; idx += 256) {
    int p = idx >> 4, ch = idx & 15;
    u16x8 val = *reinterpret_cast<const u16x8*>(&sm.TS[p * 136 + ch * 8]);
    *reinterpret_cast<u16x8*>(
        &vbf[((size_t)b * HWn + m0 + p) * 256 + o0 + ch * 8]) = val;
  }
}

// ---------------------------------------------------------------------------
// K6: gather (unchanged).
// ---------------------------------------------------------------------------
__global__ __launch_bounds__(256) void gather_cat(
    const unsigned short* __restrict__ vbf, const int* __restrict__ argb,
    unsigned short* __restrict__ catC) {
  int b = blockIdx.y;
  int tid = threadIdx.x;
  if (blockIdx.x == 16) {
    for (int u = tid; u < 2 * PADR * 512; u += 256) {
      int r = u >> 9;
      int rr = (r < PADR) ? r : (HWn + r);
      catC[((size_t)b * ROWS + rr) * 512 + (u & 511)] = 0;
    }
    return;
  }
  __shared__ int ajS[256];
  int j0 = blockIdx.x * 256;
  ajS[tid] = argb[(size_t)b * HWn + j0 + tid];
  __syncthreads();
#pragma unroll 4
  for (int u = tid; u < 256 * 32; u += 256) {
    int pl = u >> 5, ch = u & 31;
    int aj = ajS[pl];
    u16x8 val = *reinterpret_cast<const u16x8*>(
        &vbf[((size_t)b * HWn + aj) * 256 + ch * 8]);
    *reinterpret_cast<u16x8*>(
        &catC[((size_t)b * ROWS + PADR + j0 + pl) * 512 + 256 + ch * 8]) = val;
  }
}

// ---------------------------------------------------------------------------
// K7 (R14): conv3x3 implicit GEMM, NO LDS — direct global->register operands.
// Rationale: intra-block operand reuse is only 2-3x (served by L1/L2), so LDS
// staging was pure overhead (barriers + vmcnt drains pinned MfmaUtil at ~26%
// across 3 sync-structure variants). Now each wave streams independently,
// zero barriers; hipcc software-pipelines register loads across the unrolled
// kc loop. M=64 tile: acc = 32 VGPR; grid (64,2,4)=512 = 2 blocks/CU.
// Accumulation order and operands identical to R13 (bit-identical results).
// ---------------------------------------------------------------------------
__global__ __launch_bounds__(256, 2) void conv_mfma(
    const unsigned short* __restrict__ catC, const unsigned short* __restrict__ Wfb,
    const float* __restrict__ fx, const float* __restrict__ bfc,
    const float* __restrict__ star, float* __restrict__ out) {
  int m0 = blockIdx.x * 64;
  int o0 = blockIdx.y * 128;
  int b = blockIdx.z;
  int tid = threadIdx.x;
  int lane = tid & 63;
  int wv = tid >> 6;
  int wm = wv >> 1, wn = wv & 1;   // wm: o-half (64 o), wn: p-half (32 p)
  int lm = lane & 15, lq = lane >> 4;

  floatx4 acc[4][2];   // [im][in]
#pragma unroll
  for (int im = 0; im < 4; ++im)
#pragma unroll
    for (int in = 0; in < 2; ++in) acc[im][in] = (floatx4)0.0f;

  // W-boundary predicates: p%64==0 takes no dx=-1; p%64==63 no dx=+1.
  const bool e0 = (wn == 0) && (lm == 0);
  const bool e1 = (wn == 1) && (lm == 15);

  // A: Wfb[tap][o][c], tap = g*3+t, o = o0+wm*64+im*16+lm, c = kc+lq*8
  const unsigned short* abase =
      Wfb + (size_t)(o0 + wm * 64 + lm) * 512 + lq * 8;
  // B: catC[b][PADR + p + (g-1)*64 + (t-1)][c], p = m0+wn*32+in*16+lm
  const unsigned short* bbase =
      catC + ((size_t)b * ROWS + PADR + m0 + wn * 32 + lm - 65) * 512 + lq * 8;

#pragma unroll
  for (int g = 0; g < 3; ++g) {
    const unsigned short* ag = abase + (size_t)(g * 3) * 131072;
    const unsigned short* bg = bbase + (size_t)(g * 64) * 512;
#pragma unroll 2
    for (int kci = 0; kci < 16; ++kci) {
      const int kc = kci * 32;
      u16x8 af[3][4], bf_[3][2];
#pragma unroll
      for (int t = 0; t < 3; ++t)
#pragma unroll
        for (int im = 0; im < 4; ++im)
          af[t][im] = *reinterpret_cast<const u16x8*>(
              ag + (size_t)t * 131072 + im * 8192 + kc);
#pragma unroll
      for (int t = 0; t < 3; ++t)
#pragma unroll
        for (int in = 0; in < 2; ++in)
          bf_[t][in] = *reinterpret_cast<const u16x8*>(
              bg + (size_t)(t + in * 16) * 512 + kc);
      if (e0) bf_[0][0] = (u16x8)(unsigned short)0;
      if (e1) bf_[2][1] = (u16x8)(unsigned short)0;
#pragma unroll
      for (int t = 0; t < 3; ++t)
#pragma unroll
        for (int in = 0; in < 2; ++in) {
          union { u16x8 u8; bf16x8 h; } cb; cb.u8 = bf_[t][in];
#pragma unroll
          for (int im = 0; im < 4; ++im) {
            union { u16x8 u8; bf16x8 h; } ca; ca.u8 = af[t][im];
            acc[im][in] = __builtin_amdgcn_mfma_f32_16x16x32_bf16(
                ca.h, cb.h, acc[im][in], 0, 0, 0);
          }
        }
    }
  }

  // fused epilogue: out = fx + (acc + bias) * S
#pragma unroll
  for (int in = 0; in < 2; ++in) {
    int p = m0 + wn * 32 + in * 16 + lm;
    float s = star[(size_t)b * HWn + p];
#pragma unroll
    for (int im = 0; im < 4; ++im) {
      int ob = o0 + wm * 64 + im * 16 + lq * 4;
#pragma unroll
      for (int r = 0; r < 4; ++r) {
        size_t idx = ((size_t)(b * Cn + ob + r)) * HWn + p;
        out[idx] = fx[idx] + (acc[im][in][r] + bfc[ob + r]) * s;
      }
    }
  }
}

// ---------------------------------------------------------------------------
extern "C" void kernel_launch(void* const* d_in, const int* in_sizes, int n_in,
                              void* d_out, int out_size, void* d_ws, size_t ws_size,
                              hipStream_t stream) {
  const float* front_x   = (const float*)d_in[0];
  const float* cross_x   = (const float*)d_in[1];
  const float* front_hat = (const float*)d_in[2];
  const float* Wq = (const float*)d_in[3];
  const float* bq = (const float*)d_in[4];
  const float* Wk = (const float*)d_in[5];
  const float* bk = (const float*)d_in[6];
  const float* Wv = (const float*)d_in[7];
  const float* bv = (const float*)d_in[8];
  const float* Wf = (const float*)d_in[9];
  const float* bf = (const float*)d_in[10];
  float* out = (float*)d_out;

  char* ws = (char*)d_ws;
  size_t off = 0;
  auto alloc = [&](size_t bytes) -> void* {
    void* p = (void*)(ws + off);
    off += (bytes + 255) & ~(size_t)255;
    return p;
  };
  float* Wqf = (float*)alloc(8192 * sizeof(float));
  float* Wkf = (float*)alloc(8192 * sizeof(float));
  unsigned short* Wvb = (unsigned short*)alloc(65536 * sizeof(unsigned short));
  unsigned short* Wfb = (unsigned short*)alloc((size_t)9 * 256 * 512 * sizeof(unsigned short));
  float* qf  = (float*)alloc((size_t)Bn * HWn * C8 * sizeof(float));
  float* kf  = (float*)alloc((size_t)Bn * HWn * C8 * sizeof(float));
  unsigned short* qhi = (unsigned short*)alloc((size_t)Bn * HWn * C8 * 2);
  unsigned short* qlo = (unsigned short*)alloc((size_t)Bn * HWn * C8 * 2);
  unsigned short* khi = (unsigned short*)alloc((size_t)Bn * HWn * C8 * 2);
  unsigned short* klo = (unsigned short*)alloc((size_t)Bn * HWn * C8 * 2);
  float*  star = (float*)alloc((size_t)Bn * HWn * sizeof(float));
  int*    argb = (int*)alloc((size_t)Bn * HWn * sizeof(int));
  int*    cnt  = (int*)alloc(256);
  int*    list = (int*)alloc((size_t)Bn * HWn * sizeof(int));
  unsigned short* xht = (unsigned short*)alloc((size_t)Bn * HWn * 256 * 2);
  unsigned short* vbf = (unsigned short*)alloc((size_t)Bn * HWn * 256 * 2);
  unsigned short* catC = (unsigned short*)alloc((size_t)Bn * ROWS * 512 * sizeof(unsigned short));

  prep_w<<<dim3((9 * 256 * 512 + 255) / 256), dim3(256), 0, stream>>>(
      Wq, Wk, Wv, Wf, Wqf, Wkf, Wvb, Wfb, cnt);

  proj_qk<<<dim3(HWn / 64, Bn, 2), dim3(1024), 0, stream>>>(
      cross_x, front_x, Wqf, bq, Wkf, bk, qf, kf, qhi, qlo, khi, klo);

  energy_approx<<<dim3(HWn / 32, Bn), dim3(1024), 0, stream>>>(
      khi, klo, qhi, qlo, star, argb, cnt, list);

  recheck<<<dim3(256), dim3(256), 0, stream>>>(qf, kf, cnt, list, star, argb);

  cat_fx<<<dim3(HWn / 64, Cn / 64, Bn * 2), dim3(256), 0, stream>>>(
      front_x, front_hat, catC, xht);

  proj_v_mfma<<<dim3(HWn / 128, Cn / 128, Bn), dim3(256), 0, stream>>>(
      xht, Wvb, bv, vbf);

  gather_cat<<<dim3(HWn / 256 + 1, Bn), dim3(256), 0, stream>>>(vbf, argb, catC);

  conv_mfma<<<dim3(HWn / 64, Cn / 128, Bn), dim3(256), 0, stream>>>(
      catC, Wfb, front_x, bf, star, out);
}

// Round 6
// 275.164 us; speedup vs baseline: 1.4158x; 1.4158x over previous
//
#include <hip/hip_runtime.h>

#define Bn 4
#define Cn 256
#define C8 32
#define Hn 64
#define Wn 64
#define HWn 4096
#define PADR 80
#define ROWS (HWn + 2 * PADR)   // 4256 padded pixel-rows per batch
#define MARGIN 6e-3f

typedef __bf16 bf16x8 __attribute__((ext_vector_type(8)));
typedef float floatx4 __attribute__((ext_vector_type(4)));
typedef unsigned short u16x8 __attribute__((ext_vector_type(8)));

__device__ __forceinline__ unsigned short f2bf(float f) {
  union { float f; unsigned int u; } c; c.f = f;
  unsigned int u = c.u;
  return (unsigned short)((u + 0x7FFFu + ((u >> 16) & 1u)) >> 16);  // RNE
}
__device__ __forceinline__ float bf2f(unsigned short h) {
  union { unsigned int u; float f; } c; c.u = ((unsigned int)h) << 16;
  return c.f;
}
__device__ __forceinline__ void gl_lds16(const void* g, void* l) {
  __builtin_amdgcn_global_load_lds(
      (__attribute__((address_space(1))) void*)(uintptr_t)g,
      (__attribute__((address_space(3))) void*)(uintptr_t)l, 16, 0, 0);
}

// ---------------------------------------------------------------------------
// K0: weight prep + zero flagged-query counter (unchanged).
// ---------------------------------------------------------------------------
__global__ void prep_w(const float* __restrict__ Wq, const float* __restrict__ Wk,
                       const float* __restrict__ Wv, const float* __restrict__ Wf,
                       float* __restrict__ Wqf, float* __restrict__ Wkf,
                       unsigned short* __restrict__ Wvb, unsigned short* __restrict__ Wfb,
                       int* __restrict__ cnt) {
  size_t t = (size_t)blockIdx.x * 256 + threadIdx.x;
  if (t == 0) cnt[0] = 0;
  if (t < 8192) {
    int o = (int)(t / 256), c = (int)(t % 256);
    Wqf[(size_t)c * 32 + o] = Wq[t];
    Wkf[(size_t)c * 32 + o] = Wk[t];
  }
  if (t < 65536) Wvb[t] = f2bf(Wv[t]);   // [o][c] row-major already
  if (t < (size_t)9 * 256 * 512) {
    int tap = (int)(t / (256 * 512));
    int rem = (int)(t % (256 * 512));
    int o = rem / 512, ci = rem % 512;
    Wfb[t] = f2bf(Wf[((size_t)o * 512 + ci) * 9 + tap]);
  }
}

// ---------------------------------------------------------------------------
// K1: q/k projection in FP32 (unchanged from R9).
// ---------------------------------------------------------------------------
__global__ __launch_bounds__(1024) void proj_qk(
    const float* __restrict__ cross_x, const float* __restrict__ front_x,
    const float* __restrict__ Wqf, const float* __restrict__ bq,
    const float* __restrict__ Wkf, const float* __restrict__ bk,
    float* __restrict__ qf, float* __restrict__ kf,
    unsigned short* __restrict__ qhi, unsigned short* __restrict__ qlo,
    unsigned short* __restrict__ khi, unsigned short* __restrict__ klo) {
  int tid = threadIdx.x;
  int lane = tid & 63, wv = tid >> 6;    // 16 waves
  int slice = wv & 3;                    // o-slice (8 o each)
  int chunk = wv >> 2;                   // c-chunk (64 c each)
  int j = blockIdx.x * 64 + lane;
  int b = blockIdx.y;
  int z = blockIdx.z;
  const float* x = (z == 0) ? cross_x : front_x;
  const float* Wg = (z == 0) ? Wqf : Wkf;
  const float* bd = (z == 0) ? bq : bk;
  float* outp = (z == 0) ? qf : kf;
  unsigned short* hip_ = (z == 0) ? qhi : khi;
  unsigned short* lop_ = (z == 0) ? qlo : klo;
  int o0 = slice * 8;
  int c0 = chunk * 64;

  __shared__ __align__(16) float Wl[8192];        // [c][32] fp32, 32KB
  __shared__ float part[3 * 4 * 8 * 64];          // [chunk-1][slice][o][lane] 24KB

  for (int u = tid; u < 8192; u += 1024) Wl[u] = Wg[u];
  __syncthreads();

  const float* xb = x + (size_t)b * Cn * HWn + j;
  floatx4 a0 = (floatx4)0.0f, a1 = (floatx4)0.0f;
#pragma unroll 16
  for (int c = c0; c < c0 + 64; ++c) {
    float xv = xb[(size_t)c * HWn];
    floatx4 wa = *reinterpret_cast<const floatx4*>(&Wl[c * 32 + o0]);      // broadcast
    floatx4 wb = *reinterpret_cast<const floatx4*>(&Wl[c * 32 + o0 + 4]);
    a0 += wa * xv;
    a1 += wb * xv;
  }
  if (chunk > 0) {
    float* dst = &part[(((chunk - 1) * 4 + slice) * 8) * 64];
#pragma unroll
    for (int o = 0; o < 4; ++o) { dst[o * 64 + lane] = a0[o]; dst[(o + 4) * 64 + lane] = a1[o]; }
  }
  __syncthreads();
  if (chunk != 0) return;
#pragma unroll
  for (int q = 0; q < 3; ++q) {
    const float* src = &part[((q * 4 + slice) * 8) * 64];
#pragma unroll
    for (int o = 0; o < 4; ++o) { a0[o] += src[o * 64 + lane]; a1[o] += src[(o + 4) * 64 + lane]; }
  }
  float acc[8];
#pragma unroll
  for (int o = 0; o < 4; ++o) { acc[o] = a0[o] + bd[o0 + o]; acc[o + 4] = a1[o] + bd[o0 + 4 + o]; }

  float* op = outp + ((size_t)b * HWn + j) * C8 + o0;
  u16x8 hv, lv;
#pragma unroll
  for (int o = 0; o < 8; ++o) {
    op[o] = acc[o];
    unsigned short h = f2bf(acc[o]);
    hv[o] = h;
    lv[o] = f2bf(acc[o] - bf2f(h));
  }
  *reinterpret_cast<u16x8*>(hip_ + ((size_t)b * HWn + j) * C8 + o0) = hv;
  *reinterpret_cast<u16x8*>(lop_ + ((size_t)b * HWn + j) * C8 + o0) = lv;
}

// ---------------------------------------------------------------------------
// K2: approximate energy via split-bf16 MFMA (R10: branchless med3 tracking,
// index packed in mantissa LSBs, 32-query tile for 2 blocks/CU).
// ---------------------------------------------------------------------------
__global__ __launch_bounds__(1024) void energy_approx(
    const unsigned short* __restrict__ khi, const unsigned short* __restrict__ klo,
    const unsigned short* __restrict__ qhi, const unsigned short* __restrict__ qlo,
    float* __restrict__ star, int* __restrict__ argb,
    int* __restrict__ cnt, int* __restrict__ list) {
  int b = blockIdx.y;
  int j0 = blockIdx.x * 32;
  int tid = threadIdx.x;
  int lane = tid & 63, wv = tid >> 6;   // wv 0..15
  int lm = lane & 15, lq = lane >> 4;

  __shared__ float bv1S[16][32];
  __shared__ int   bi1S[16][32];
  __shared__ float bv2S[16][32];

  bf16x8 qh[2], ql[2];
#pragma unroll
  for (int s = 0; s < 2; ++s) {
    int j = j0 + s * 16 + lm;
    qh[s] = *reinterpret_cast<const bf16x8*>(qhi + ((size_t)b * HWn + j) * 32 + lq * 8);
    ql[s] = *reinterpret_cast<const bf16x8*>(qlo + ((size_t)b * HWn + j) * 32 + lq * 8);
  }
  const unsigned short* kh_base = khi + (size_t)b * HWn * 32 + lq * 8;
  const unsigned short* kl_base = klo + (size_t)b * HWn * 32 + lq * 8;

  float b1[2], b2[2];
#pragma unroll
  for (int s = 0; s < 2; ++s) { b1[s] = -3.0e38f; b2[s] = -3.0e38f; }

  int ibase = wv * 256;
#pragma unroll 4
  for (int it = 0; it < 16; ++it) {
    int i0 = ibase + it * 16;
    bf16x8 ah = *reinterpret_cast<const bf16x8*>(kh_base + (size_t)(i0 + lm) * 32);
    bf16x8 al = *reinterpret_cast<const bf16x8*>(kl_base + (size_t)(i0 + lm) * 32);
#pragma unroll
    for (int s = 0; s < 2; ++s) {
      floatx4 acc = (floatx4)0.0f;
      acc = __builtin_amdgcn_mfma_f32_16x16x32_bf16(ah, qh[s], acc, 0, 0, 0);
      acc = __builtin_amdgcn_mfma_f32_16x16x32_bf16(ah, ql[s], acc, 0, 0, 0);
      acc = __builtin_amdgcn_mfma_f32_16x16x32_bf16(al, qh[s], acc, 0, 0, 0);
#pragma unroll
      for (int r = 0; r < 4; ++r) {
        unsigned code = (unsigned)(it * 4 + r);   // SGPR-uniform per (it,r)
        union { float f; unsigned u; } cv; cv.f = acc[r];
        cv.u = (cv.u & ~63u) | code;              // v_and_or_b32
        float vp = cv.f;
        // exact new second-best: median(vp, b1_old, b2_old)
        b2[s] = __builtin_amdgcn_fmed3f(vp, b1[s], b2[s]);
        b1[s] = fmaxf(b1[s], vp);
      }
    }
  }
  int i1[2];
#pragma unroll
  for (int s = 0; s < 2; ++s) {
    union { float f; unsigned u; } cv; cv.f = b1[s];
    unsigned code = cv.u & 63u;                   // (it<<2)|r of the winner
    i1[s] = ibase + (int)(code >> 2) * 16 + lq * 4 + (int)(code & 3u);
  }
#pragma unroll
  for (int s = 0; s < 2; ++s) {
#pragma unroll
    for (int m = 16; m <= 32; m <<= 1) {
      float ob1 = __shfl_xor(b1[s], m, 64);
      int oi1 = __shfl_xor(i1[s], m, 64);
      float ob2 = __shfl_xor(b2[s], m, 64);
      float c2;
      if (ob1 > b1[s] || (ob1 == b1[s] && oi1 < i1[s])) {
        c2 = fmaxf(b1[s], ob2);
        b1[s] = ob1; i1[s] = oi1;
      } else {
        c2 = fmaxf(ob1, b2[s]);
      }
      b2[s] = c2;
    }
    if (lq == 0) {
      bv1S[wv][s * 16 + lm] = b1[s];
      bi1S[wv][s * 16 + lm] = i1[s];
      bv2S[wv][s * 16 + lm] = b2[s];
    }
  }
  __syncthreads();
  if (tid < 32) {
    float B1 = bv1S[0][tid];
    int I1 = bi1S[0][tid];
    float B2 = bv2S[0][tid];
#pragma unroll
    for (int w = 1; w < 16; ++w) {
      float v1 = bv1S[w][tid];
      int ii = bi1S[w][tid];
      float v2 = bv2S[w][tid];
      if (v1 > B1) { B2 = fmaxf(B1, v2); B1 = v1; I1 = ii; }
      else B2 = fmaxf(B2, v1);
    }
    size_t o = (size_t)b * HWn + j0 + tid;
    union { float f; unsigned u; } cs; cs.f = B1;
    cs.u &= ~63u;                                 // strip packed index bits
    star[o] = cs.f;
    argb[o] = I1;
    if (B1 - B2 < MARGIN) {
      int slot = atomicAdd(cnt, 1);
      list[slot] = (b << 12) | (j0 + (int)tid);
    }
  }
}

// ---------------------------------------------------------------------------
// K3: recheck — fp64 accumulation over fp32 q,k (unchanged from R9).
// ---------------------------------------------------------------------------
__global__ __launch_bounds__(256) void recheck(
    const float* __restrict__ qf, const float* __restrict__ kf,
    const int* __restrict__ cnt, const int* __restrict__ list,
    float* __restrict__ star, int* __restrict__ argb) {
  __shared__ double bvS[4];
  __shared__ int biS[4];
  int n = cnt[0];
  int tid = threadIdx.x;
  int lane = tid & 63, wv = tid >> 6;
  for (int idx = blockIdx.x; idx < n; idx += gridDim.x) {
    int e = list[idx];
    int b = e >> 12, j = e & 4095;
    const float* qp = qf + ((size_t)b * HWn + j) * 32;
    double qj[32];
#pragma unroll
    for (int o = 0; o < 32; ++o) qj[o] = (double)qp[o];
    double best = -1.0e300;
    int bi = 1 << 30;
    for (int i = tid; i < HWn; i += 256) {
      const float* kp = kf + ((size_t)b * HWn + i) * 32;
      double s = 0.0;
#pragma unroll
      for (int o = 0; o < 32; ++o) s += (double)kp[o] * qj[o];
      if (s > best) { best = s; bi = i; }
    }
#pragma unroll
    for (int m = 1; m < 64; m <<= 1) {
      double ob = __shfl_xor(best, m, 64);
      int oi = __shfl_xor(bi, m, 64);
      if (ob > best || (ob == best && oi < bi)) { best = ob; bi = oi; }
    }
    if (lane == 0) { bvS[wv] = best; biS[wv] = bi; }
    __syncthreads();
    if (tid == 0) {
#pragma unroll
      for (int w = 1; w < 4; ++w) {
        if (bvS[w] > best || (bvS[w] == best && biS[w] < bi)) {
          best = bvS[w]; bi = biS[w];
        }
      }
      star[(size_t)b * HWn + j] = (float)best;
      argb[(size_t)b * HWn + j] = bi;
    }
    __syncthreads();
  }
}

// ---------------------------------------------------------------------------
// K4: transpose to bf16 pixel-major (unchanged).
// ---------------------------------------------------------------------------
__global__ __launch_bounds__(256) void cat_fx(
    const float* __restrict__ fx, const float* __restrict__ fxh,
    unsigned short* __restrict__ catC, unsigned short* __restrict__ xht) {
  int j0 = blockIdx.x * 64;
  int ci0 = blockIdx.y * 64;
  int b = blockIdx.z >> 1;
  int which = blockIdx.z & 1;
  int tid = threadIdx.x;
  __shared__ unsigned short tile[64][66];

  const float* src = (which == 0) ? fx : fxh;
  for (int u = tid; u < 4096; u += 256) {
    int cl = u >> 6, hw_l = u & 63;
    tile[cl][hw_l] = f2bf(src[((size_t)(b * Cn + ci0 + cl)) * HWn + j0 + hw_l]);
  }
  __syncthreads();
  if (which == 0) {
    for (int u = tid; u < 4096; u += 256) {
      int hw_l = u >> 6, cl = u & 63;
      catC[((size_t)b * ROWS + PADR + j0 + hw_l) * 512 + ci0 + cl] = tile[cl][hw_l];
    }
  } else {
    for (int u = tid; u < 4096; u += 256) {
      int hw_l = u >> 6, cl = u & 63;
      xht[((size_t)b * HWn + j0 + hw_l) * 256 + ci0 + cl] = tile[cl][hw_l];
    }
  }
}

// ---------------------------------------------------------------------------
// K5: v projection as bf16 MFMA GEMM, XOR-swizzled LDS (R13 counted-vmcnt).
// ---------------------------------------------------------------------------
__global__ __launch_bounds__(256) void proj_v_mfma(
    const unsigned short* __restrict__ xht, const unsigned short* __restrict__ Wvb,
    const float* __restrict__ bv, unsigned short* __restrict__ vbf) {
  int m0 = blockIdx.x * 128;
  int o0 = blockIdx.y * 128;
  int b = blockIdx.z;
  int tid = threadIdx.x;
  int lane = tid & 63, wv = tid >> 6;
  int wm = wv >> 1, wn = wv & 1;
  int lm = lane & 15, lq = lane >> 4;

  union SMu {
    struct { unsigned short A[2][128 * 32]; unsigned short B[2][128 * 32]; } st;
    unsigned short TS[128 * 136];
  };
  __shared__ __align__(16) SMu sm;

  floatx4 acc[4][4];
#pragma unroll
  for (int im = 0; im < 4; ++im)
#pragma unroll
    for (int in = 0; in < 4; ++in) acc[im][in] = (floatx4)0.0f;

  const int srow = lane >> 2;
  const int soff = (((lane & 3) ^ ((lane >> 3) & 3)) * 8);   // swizzled source chunk
  const int sa = (lq ^ ((lm >> 1) & 3)) * 8;                 // swizzled read column
  const unsigned short* ag = Wvb + (size_t)o0 * 256;
  const unsigned short* bg = xht + ((size_t)b * HWn + m0) * 256;

  auto STAGE = [&](int buf, int kc) {
#pragma unroll
    for (int i = 0; i < 2; ++i) {
      int r0 = wv * 32 + i * 16;
      gl_lds16(ag + ((size_t)(r0 + srow)) * 256 + kc + soff, &sm.st.A[buf][r0 * 32]);
      gl_lds16(bg + ((size_t)(r0 + srow)) * 256 + kc + soff, &sm.st.B[buf][r0 * 32]);
    }
  };
  auto COMPUTE = [&](int buf) {
    bf16x8 afr[4];
#pragma unroll
    for (int im = 0; im < 4; ++im)
      afr[im] = *reinterpret_cast<const bf16x8*>(
          &sm.st.A[buf][(wm * 64 + im * 16 + lm) * 32 + sa]);
#pragma unroll
    for (int in = 0; in < 4; ++in) {
      bf16x8 bfr = *reinterpret_cast<const bf16x8*>(
          &sm.st.B[buf][(wn * 64 + in * 16 + lm) * 32 + sa]);
#pragma unroll
      for (int im = 0; im < 4; ++im)
        acc[im][in] = __builtin_amdgcn_mfma_f32_16x16x32_bf16(
            afr[im], bfr, acc[im][in], 0, 0, 0);
    }
  };

  STAGE(0, 0);
#pragma unroll 2
  for (int st = 0; st < 8; ++st) {
    __builtin_amdgcn_s_barrier();            // buf[(st+1)&1] free to overwrite
    if (st < 7) {
      STAGE((st + 1) & 1, (st + 1) * 32);
      asm volatile("s_waitcnt vmcnt(4)" ::: "memory");   // tile st landed
    } else {
      asm volatile("s_waitcnt vmcnt(0)" ::: "memory");
    }
    __builtin_amdgcn_s_barrier();
    __builtin_amdgcn_sched_barrier(0);
    COMPUTE(st & 1);
  }
  __builtin_amdgcn_s_barrier();   // all waves done reading before TS overwrite

  // epilogue: TS aliases the (now dead) stage buffers.
#pragma unroll
  for (int in = 0; in < 4; ++in) {
    int pl = wn * 64 + in * 16 + lm;
#pragma unroll
    for (int im = 0; im < 4; ++im) {
#pragma unroll
      for (int r = 0; r < 4; ++r) {
        int ol = wm * 64 + im * 16 + lq * 4 + r;
        sm.TS[pl * 136 + ol] = f2bf(acc[im][in][r] + bv[o0 + ol]);
      }
    }
  }
  __syncthreads();
  for (int idx = tid; idx < 128 * 16; idx += 256) {
    int p = idx >> 4, ch = idx & 15;
    u16x8 val = *reinterpret_cast<const u16x8*>(&sm.TS[p * 136 + ch * 8]);
    *reinterpret_cast<u16x8*>(
        &vbf[((size_t)b * HWn + m0 + p) * 256 + o0 + ch * 8]) = val;
  }
}

// ---------------------------------------------------------------------------
// K6: gather (unchanged).
// ---------------------------------------------------------------------------
__global__ __launch_bounds__(256) void gather_cat(
    const unsigned short* __restrict__ vbf, const int* __restrict__ argb,
    unsigned short* __restrict__ catC) {
  int b = blockIdx.y;
  int tid = threadIdx.x;
  if (blockIdx.x == 16) {
    for (int u = tid; u < 2 * PADR * 512; u += 256) {
      int r = u >> 9;
      int rr = (r < PADR) ? r : (HWn + r);
      catC[((size_t)b * ROWS + rr) * 512 + (u & 511)] = 0;
    }
    return;
  }
  __shared__ int ajS[256];
  int j0 = blockIdx.x * 256;
  ajS[tid] = argb[(size_t)b * HWn + j0 + tid];
  __syncthreads();
#pragma unroll 4
  for (int u = tid; u < 256 * 32; u += 256) {
    int pl = u >> 5, ch = u & 31;
    int aj = ajS[pl];
    u16x8 val = *reinterpret_cast<const u16x8*>(
        &vbf[((size_t)b * HWn + aj) * 256 + ch * 8]);
    *reinterpret_cast<u16x8*>(
        &catC[((size_t)b * ROWS + PADR + j0 + pl) * 512 + 256 + ch * 8]) = val;
  }
}

// ---------------------------------------------------------------------------
// K7 (R15): conv3x3 implicit GEMM, M=256 x o=256 tile, 16 waves (4x4),
// g split across blocks, bf16 partials + combine (R11 numerics).
// Geometry fix: staged bytes/MFMA = 65KB/768 = 0.085 (2x better than R11's
// 33KB/192) -> per-CU L2 delivery (~7.8us) finally balances MFMA (~6.2us).
// Grid (16,1,12) = 192 blocks, 1 block/CU, LDS 133KB dbuf, counted vmcnt.
// ---------------------------------------------------------------------------
__global__ __launch_bounds__(1024) void conv_mfma(
    const unsigned short* __restrict__ catC, const unsigned short* __restrict__ Wfb,
    unsigned short* __restrict__ Pg) {
  int m0 = blockIdx.x * 256;
  int bz = blockIdx.z;
  int b = bz / 3, g = bz % 3;      // g = dy+1
  int dy = g - 1;
  int tid = threadIdx.x;
  int lane = tid & 63;
  int wv = tid >> 6;               // 16 waves
  int wm = wv >> 2, wn = wv & 3;   // wm: o-quarter (64 o), wn: p-quarter (64 p)
  int lm = lane & 15, lq = lane >> 4;

  __shared__ __align__(16) unsigned short AS[2][3 * 256 * 32];  // 2x48KB
  __shared__ __align__(16) unsigned short BS[2][272 * 32];      // 2x17KB

  floatx4 acc[4][4];
#pragma unroll
  for (int im = 0; im < 4; ++im)
#pragma unroll
    for (int in = 0; in < 4; ++in) acc[im][in] = (floatx4)0.0f;

  const int srow = lane >> 2;
  const int soff = (((lane & 3) ^ ((lane >> 3) & 3)) * 8);   // swizzled source chunk
  const int sa = (lq ^ ((lm >> 1) & 3)) * 8;                 // A read column
  const unsigned short* catb =
      catC + ((size_t)b * ROWS + PADR + m0 + dy * 64 - 1) * 512;
  const unsigned short* wfg = Wfb + (size_t)(g * 3) * 256 * 512;

  // 65 staging slots/step: 0..47 = A (t = slot>>4, o-group = slot&15),
  // 48..64 = B (17 groups of 16 rows, covers 272 rows >= 258 needed).
  auto STAGE = [&](int buf, int kci) {
    int kc = kci * 32;
    for (int i = wv; i < 65; i += 16) {
      if (i < 48) {
        int t = i >> 4, s = i & 15;
        gl_lds16(wfg + ((size_t)(t * 256 + s * 16 + srow)) * 512 + kc + soff,
                 &AS[buf][(t * 256 + s * 16) * 32]);
      } else {
        int s = i - 48;
        gl_lds16(catb + ((size_t)(s * 16 + srow)) * 512 + kc + soff,
                 &BS[buf][(s * 16) * 32]);
      }
    }
  };
  auto COMPUTE = [&](int buf) {
#pragma unroll
    for (int t = 0; t < 3; ++t) {   // t = dx+1
      bf16x8 afr[4];
#pragma unroll
      for (int im = 0; im < 4; ++im)
        afr[im] = *reinterpret_cast<const bf16x8*>(
            &AS[buf][(t * 256 + wm * 64 + im * 16 + lm) * 32 + sa]);
#pragma unroll
      for (int in = 0; in < 4; ++in) {
        int u = wn * 64 + in * 16 + lm + t;   // row in BS
        int sb = (lq ^ ((u >> 1) & 3)) * 8;
        u16x8 braw = *reinterpret_cast<const u16x8*>(&BS[buf][u * 32 + sb]);
        if ((t == 0 && in == 0 && lm == 0) ||
            (t == 2 && in == 3 && lm == 15))
          braw = (u16x8)(unsigned short)0;
        union { u16x8 u8; bf16x8 h; } cvt; cvt.u8 = braw;
#pragma unroll
        for (int im = 0; im < 4; ++im)
          acc[im][in] = __builtin_amdgcn_mfma_f32_16x16x32_bf16(
              afr[im], cvt.h, acc[im][in], 0, 0, 0);
      }
    }
  };

  STAGE(0, 0);
#pragma unroll 2
  for (int st = 0; st < 16; ++st) {
    asm volatile("s_waitcnt lgkmcnt(0)" ::: "memory");  // own ds_reads retired
    __builtin_amdgcn_s_barrier();            // buf[(st+1)&1] free to overwrite
    if (st < 15) {
      STAGE((st + 1) & 1, st + 1);
      asm volatile("s_waitcnt vmcnt(4)" ::: "memory");  // tile st's loads landed
    } else {
      asm volatile("s_waitcnt vmcnt(0)" ::: "memory");
    }
    __builtin_amdgcn_s_barrier();
    __builtin_amdgcn_sched_barrier(0);
    COMPUTE(st & 1);
  }

  unsigned short* P = Pg + ((size_t)(g * Bn + b) * Cn) * HWn;
#pragma unroll
  for (int in = 0; in < 4; ++in) {
    int p = m0 + wn * 64 + in * 16 + lm;
#pragma unroll
    for (int im = 0; im < 4; ++im) {
      int ob = wm * 64 + im * 16 + lq * 4;
#pragma unroll
      for (int r = 0; r < 4; ++r)
        P[(size_t)(ob + r) * HWn + p] = f2bf(acc[im][in][r]);
    }
  }
}

// ---------------------------------------------------------------------------
// K8: combine: out = fx + (P0+P1+P2 + bf)*S over bf16 partials, 8 elem/thread.
// ---------------------------------------------------------------------------
__global__ __launch_bounds__(256) void combine(
    const unsigned short* __restrict__ Pg, const float* __restrict__ fx,
    const float* __restrict__ bf, const float* __restrict__ star,
    float* __restrict__ out) {
  size_t e = ((size_t)blockIdx.x * 256 + threadIdx.x) * 8;
  int p = (int)(e & 4095);
  int bo = (int)(e >> 12);
  int o = bo & 255, b = bo >> 8;
  const size_t gs = (size_t)Bn * Cn * HWn;
  u16x8 q0 = *reinterpret_cast<const u16x8*>(Pg + e);
  u16x8 q1 = *reinterpret_cast<const u16x8*>(Pg + gs + e);
  u16x8 q2 = *reinterpret_cast<const u16x8*>(Pg + 2 * gs + e);
  float bias = bf[o];
  const float* sp = star + (size_t)b * HWn + p;
  const float* fp = fx + e;
  float* op = out + e;
#pragma unroll
  for (int h = 0; h < 2; ++h) {
    floatx4 s = *reinterpret_cast<const floatx4*>(sp + h * 4);
    floatx4 f = *reinterpret_cast<const floatx4*>(fp + h * 4);
    floatx4 r;
#pragma unroll
    for (int i = 0; i < 4; ++i) {
      int k = h * 4 + i;
      float a = bf2f(q0[k]) + bf2f(q1[k]) + bf2f(q2[k]);
      r[i] = f[i] + (a + bias) * s[i];
    }
    *reinterpret_cast<floatx4*>(op + h * 4) = r;
  }
}

// ---------------------------------------------------------------------------
extern "C" void kernel_launch(void* const* d_in, const int* in_sizes, int n_in,
                              void* d_out, int out_size, void* d_ws, size_t ws_size,
                              hipStream_t stream) {
  const float* front_x   = (const float*)d_in[0];
  const float* cross_x   = (const float*)d_in[1];
  const float* front_hat = (const float*)d_in[2];
  const float* Wq = (const float*)d_in[3];
  const float* bq = (const float*)d_in[4];
  const float* Wk = (const float*)d_in[5];
  const float* bk = (const float*)d_in[6];
  const float* Wv = (const float*)d_in[7];
  const float* bv = (const float*)d_in[8];
  const float* Wf = (const float*)d_in[9];
  const float* bf = (const float*)d_in[10];
  float* out = (float*)d_out;

  char* ws = (char*)d_ws;
  size_t off = 0;
  auto alloc = [&](size_t bytes) -> void* {
    void* p = (void*)(ws + off);
    off += (bytes + 255) & ~(size_t)255;
    return p;
  };
  float* Wqf = (float*)alloc(8192 * sizeof(float));
  float* Wkf = (float*)alloc(8192 * sizeof(float));
  unsigned short* Wvb = (unsigned short*)alloc(65536 * sizeof(unsigned short));
  unsigned short* Wfb = (unsigned short*)alloc((size_t)9 * 256 * 512 * sizeof(unsigned short));
  float* qf  = (float*)alloc((size_t)Bn * HWn * C8 * sizeof(float));
  float* kf  = (float*)alloc((size_t)Bn * HWn * C8 * sizeof(float));
  unsigned short* qhi = (unsigned short*)alloc((size_t)Bn * HWn * C8 * 2);
  unsigned short* qlo = (unsigned short*)alloc((size_t)Bn * HWn * C8 * 2);
  unsigned short* khi = (unsigned short*)alloc((size_t)Bn * HWn * C8 * 2);
  unsigned short* klo = (unsigned short*)alloc((size_t)Bn * HWn * C8 * 2);
  float*  star = (float*)alloc((size_t)Bn * HWn * sizeof(float));
  int*    argb = (int*)alloc((size_t)Bn * HWn * sizeof(int));
  int*    cnt  = (int*)alloc(256);
  int*    list = (int*)alloc((size_t)Bn * HWn * sizeof(int));
  unsigned short* xht = (unsigned short*)alloc((size_t)Bn * HWn * 256 * 2);
  unsigned short* vbf = (unsigned short*)alloc((size_t)Bn * HWn * 256 * 2);
  unsigned short* catC = (unsigned short*)alloc((size_t)Bn * ROWS * 512 * sizeof(unsigned short));
  unsigned short* Pg = (unsigned short*)alloc((size_t)3 * Bn * Cn * HWn * 2);  // 25 MB bf16

  prep_w<<<dim3((9 * 256 * 512 + 255) / 256), dim3(256), 0, stream>>>(
      Wq, Wk, Wv, Wf, Wqf, Wkf, Wvb, Wfb, cnt);

  proj_qk<<<dim3(HWn / 64, Bn, 2), dim3(1024), 0, stream>>>(
      cross_x, front_x, Wqf, bq, Wkf, bk, qf, kf, qhi, qlo, khi, klo);

  energy_approx<<<dim3(HWn / 32, Bn), dim3(1024), 0, stream>>>(
      khi, klo, qhi, qlo, star, argb, cnt, list);

  recheck<<<dim3(256), dim3(256), 0, stream>>>(qf, kf, cnt, list, star, argb);

  cat_fx<<<dim3(HWn / 64, Cn / 64, Bn * 2), dim3(256), 0, stream>>>(
      front_x, front_hat, catC, xht);

  proj_v_mfma<<<dim3(HWn / 128, Cn / 128, Bn), dim3(256), 0, stream>>>(
      xht, Wvb, bv, vbf);

  gather_cat<<<dim3(HWn / 256 + 1, Bn), dim3(256), 0, stream>>>(vbf, argb, catC);

  conv_mfma<<<dim3(HWn / 256, 1, Bn * 3), dim3(1024), 0, stream>>>(
      catC, Wfb, Pg);

  combine<<<dim3((Bn * Cn * HWn / 8) / 256), dim3(256), 0, stream>>>(
      Pg, front_x, bf, star, out);
}

// Round 7
// 240.894 us; speedup vs baseline: 1.6173x; 1.1423x over previous
//
#include <hip/hip_runtime.h>

#define Bn 4
#define Cn 256
#define C8 32
#define Hn 64
#define Wn 64
#define HWn 4096
#define PADR 80
#define ROWS (HWn + 2 * PADR)   // 4256 padded pixel-rows per batch
#define MARGIN 6e-3f

typedef __bf16 bf16x8 __attribute__((ext_vector_type(8)));
typedef float floatx4 __attribute__((ext_vector_type(4)));
typedef unsigned short u16x8 __attribute__((ext_vector_type(8)));

__device__ __forceinline__ unsigned short f2bf(float f) {
  union { float f; unsigned int u; } c; c.f = f;
  unsigned int u = c.u;
  return (unsigned short)((u + 0x7FFFu + ((u >> 16) & 1u)) >> 16);  // RNE
}
__device__ __forceinline__ float bf2f(unsigned short h) {
  union { unsigned int u; float f; } c; c.u = ((unsigned int)h) << 16;
  return c.f;
}
__device__ __forceinline__ void gl_lds16(const void* g, void* l) {
  __builtin_amdgcn_global_load_lds(
      (__attribute__((address_space(1))) void*)(uintptr_t)g,
      (__attribute__((address_space(3))) void*)(uintptr_t)l, 16, 0, 0);
}

// ---------------------------------------------------------------------------
// K0: weight prep + zero flagged-query counter (unchanged).
// ---------------------------------------------------------------------------
__global__ void prep_w(const float* __restrict__ Wq, const float* __restrict__ Wk,
                       const float* __restrict__ Wv, const float* __restrict__ Wf,
                       float* __restrict__ Wqf, float* __restrict__ Wkf,
                       unsigned short* __restrict__ Wvb, unsigned short* __restrict__ Wfb,
                       int* __restrict__ cnt) {
  size_t t = (size_t)blockIdx.x * 256 + threadIdx.x;
  if (t == 0) cnt[0] = 0;
  if (t < 8192) {
    int o = (int)(t / 256), c = (int)(t % 256);
    Wqf[(size_t)c * 32 + o] = Wq[t];
    Wkf[(size_t)c * 32 + o] = Wk[t];
  }
  if (t < 65536) Wvb[t] = f2bf(Wv[t]);   // [o][c] row-major already
  if (t < (size_t)9 * 256 * 512) {
    int tap = (int)(t / (256 * 512));
    int rem = (int)(t % (256 * 512));
    int o = rem / 512, ci = rem % 512;
    Wfb[t] = f2bf(Wf[((size_t)o * 512 + ci) * 9 + tap]);
  }
}

// ---------------------------------------------------------------------------
// K1: q/k projection in FP32 (unchanged from R9).
// ---------------------------------------------------------------------------
__global__ __launch_bounds__(1024) void proj_qk(
    const float* __restrict__ cross_x, const float* __restrict__ front_x,
    const float* __restrict__ Wqf, const float* __restrict__ bq,
    const float* __restrict__ Wkf, const float* __restrict__ bk,
    float* __restrict__ qf, float* __restrict__ kf,
    unsigned short* __restrict__ qhi, unsigned short* __restrict__ qlo,
    unsigned short* __restrict__ khi, unsigned short* __restrict__ klo) {
  int tid = threadIdx.x;
  int lane = tid & 63, wv = tid >> 6;    // 16 waves
  int slice = wv & 3;                    // o-slice (8 o each)
  int chunk = wv >> 2;                   // c-chunk (64 c each)
  int j = blockIdx.x * 64 + lane;
  int b = blockIdx.y;
  int z = blockIdx.z;
  const float* x = (z == 0) ? cross_x : front_x;
  const float* Wg = (z == 0) ? Wqf : Wkf;
  const float* bd = (z == 0) ? bq : bk;
  float* outp = (z == 0) ? qf : kf;
  unsigned short* hip_ = (z == 0) ? qhi : khi;
  unsigned short* lop_ = (z == 0) ? qlo : klo;
  int o0 = slice * 8;
  int c0 = chunk * 64;

  __shared__ __align__(16) float Wl[8192];        // [c][32] fp32, 32KB
  __shared__ float part[3 * 4 * 8 * 64];          // [chunk-1][slice][o][lane] 24KB

  for (int u = tid; u < 8192; u += 1024) Wl[u] = Wg[u];
  __syncthreads();

  const float* xb = x + (size_t)b * Cn * HWn + j;
  floatx4 a0 = (floatx4)0.0f, a1 = (floatx4)0.0f;
#pragma unroll 16
  for (int c = c0; c < c0 + 64; ++c) {
    float xv = xb[(size_t)c * HWn];
    floatx4 wa = *reinterpret_cast<const floatx4*>(&Wl[c * 32 + o0]);      // broadcast
    floatx4 wb = *reinterpret_cast<const floatx4*>(&Wl[c * 32 + o0 + 4]);
    a0 += wa * xv;
    a1 += wb * xv;
  }
  if (chunk > 0) {
    float* dst = &part[(((chunk - 1) * 4 + slice) * 8) * 64];
#pragma unroll
    for (int o = 0; o < 4; ++o) { dst[o * 64 + lane] = a0[o]; dst[(o + 4) * 64 + lane] = a1[o]; }
  }
  __syncthreads();
  if (chunk != 0) return;
#pragma unroll
  for (int q = 0; q < 3; ++q) {
    const float* src = &part[((q * 4 + slice) * 8) * 64];
#pragma unroll
    for (int o = 0; o < 4; ++o) { a0[o] += src[o * 64 + lane]; a1[o] += src[(o + 4) * 64 + lane]; }
  }
  float acc[8];
#pragma unroll
  for (int o = 0; o < 4; ++o) { acc[o] = a0[o] + bd[o0 + o]; acc[o + 4] = a1[o] + bd[o0 + 4 + o]; }

  float* op = outp + ((size_t)b * HWn + j) * C8 + o0;
  u16x8 hv, lv;
#pragma unroll
  for (int o = 0; o < 8; ++o) {
    op[o] = acc[o];
    unsigned short h = f2bf(acc[o]);
    hv[o] = h;
    lv[o] = f2bf(acc[o] - bf2f(h));
  }
  *reinterpret_cast<u16x8*>(hip_ + ((size_t)b * HWn + j) * C8 + o0) = hv;
  *reinterpret_cast<u16x8*>(lop_ + ((size_t)b * HWn + j) * C8 + o0) = lv;
}

// ---------------------------------------------------------------------------
// K2: approximate energy via split-bf16 MFMA (R10: branchless med3 tracking,
// index packed in mantissa LSBs, 32-query tile for 2 blocks/CU).
// ---------------------------------------------------------------------------
__global__ __launch_bounds__(1024) void energy_approx(
    const unsigned short* __restrict__ khi, const unsigned short* __restrict__ klo,
    const unsigned short* __restrict__ qhi, const unsigned short* __restrict__ qlo,
    float* __restrict__ star, int* __restrict__ argb,
    int* __restrict__ cnt, int* __restrict__ list) {
  int b = blockIdx.y;
  int j0 = blockIdx.x * 32;
  int tid = threadIdx.x;
  int lane = tid & 63, wv = tid >> 6;   // wv 0..15
  int lm = lane & 15, lq = lane >> 4;

  __shared__ float bv1S[16][32];
  __shared__ int   bi1S[16][32];
  __shared__ float bv2S[16][32];

  bf16x8 qh[2], ql[2];
#pragma unroll
  for (int s = 0; s < 2; ++s) {
    int j = j0 + s * 16 + lm;
    qh[s] = *reinterpret_cast<const bf16x8*>(qhi + ((size_t)b * HWn + j) * 32 + lq * 8);
    ql[s] = *reinterpret_cast<const bf16x8*>(qlo + ((size_t)b * HWn + j) * 32 + lq * 8);
  }
  const unsigned short* kh_base = khi + (size_t)b * HWn * 32 + lq * 8;
  const unsigned short* kl_base = klo + (size_t)b * HWn * 32 + lq * 8;

  float b1[2], b2[2];
#pragma unroll
  for (int s = 0; s < 2; ++s) { b1[s] = -3.0e38f; b2[s] = -3.0e38f; }

  int ibase = wv * 256;
#pragma unroll 4
  for (int it = 0; it < 16; ++it) {
    int i0 = ibase + it * 16;
    bf16x8 ah = *reinterpret_cast<const bf16x8*>(kh_base + (size_t)(i0 + lm) * 32);
    bf16x8 al = *reinterpret_cast<const bf16x8*>(kl_base + (size_t)(i0 + lm) * 32);
#pragma unroll
    for (int s = 0; s < 2; ++s) {
      floatx4 acc = (floatx4)0.0f;
      acc = __builtin_amdgcn_mfma_f32_16x16x32_bf16(ah, qh[s], acc, 0, 0, 0);
      acc = __builtin_amdgcn_mfma_f32_16x16x32_bf16(ah, ql[s], acc, 0, 0, 0);
      acc = __builtin_amdgcn_mfma_f32_16x16x32_bf16(al, qh[s], acc, 0, 0, 0);
#pragma unroll
      for (int r = 0; r < 4; ++r) {
        unsigned code = (unsigned)(it * 4 + r);   // SGPR-uniform per (it,r)
        union { float f; unsigned u; } cv; cv.f = acc[r];
        cv.u = (cv.u & ~63u) | code;              // v_and_or_b32
        float vp = cv.f;
        // exact new second-best: median(vp, b1_old, b2_old)
        b2[s] = __builtin_amdgcn_fmed3f(vp, b1[s], b2[s]);
        b1[s] = fmaxf(b1[s], vp);
      }
    }
  }
  int i1[2];
#pragma unroll
  for (int s = 0; s < 2; ++s) {
    union { float f; unsigned u; } cv; cv.f = b1[s];
    unsigned code = cv.u & 63u;                   // (it<<2)|r of the winner
    i1[s] = ibase + (int)(code >> 2) * 16 + lq * 4 + (int)(code & 3u);
  }
#pragma unroll
  for (int s = 0; s < 2; ++s) {
#pragma unroll
    for (int m = 16; m <= 32; m <<= 1) {
      float ob1 = __shfl_xor(b1[s], m, 64);
      int oi1 = __shfl_xor(i1[s], m, 64);
      float ob2 = __shfl_xor(b2[s], m, 64);
      float c2;
      if (ob1 > b1[s] || (ob1 == b1[s] && oi1 < i1[s])) {
        c2 = fmaxf(b1[s], ob2);
        b1[s] = ob1; i1[s] = oi1;
      } else {
        c2 = fmaxf(ob1, b2[s]);
      }
      b2[s] = c2;
    }
    if (lq == 0) {
      bv1S[wv][s * 16 + lm] = b1[s];
      bi1S[wv][s * 16 + lm] = i1[s];
      bv2S[wv][s * 16 + lm] = b2[s];
    }
  }
  __syncthreads();
  if (tid < 32) {
    float B1 = bv1S[0][tid];
    int I1 = bi1S[0][tid];
    float B2 = bv2S[0][tid];
#pragma unroll
    for (int w = 1; w < 16; ++w) {
      float v1 = bv1S[w][tid];
      int ii = bi1S[w][tid];
      float v2 = bv2S[w][tid];
      if (v1 > B1) { B2 = fmaxf(B1, v2); B1 = v1; I1 = ii; }
      else B2 = fmaxf(B2, v1);
    }
    size_t o = (size_t)b * HWn + j0 + tid;
    union { float f; unsigned u; } cs; cs.f = B1;
    cs.u &= ~63u;                                 // strip packed index bits
    star[o] = cs.f;
    argb[o] = I1;
    if (B1 - B2 < MARGIN) {
      int slot = atomicAdd(cnt, 1);
      list[slot] = (b << 12) | (j0 + (int)tid);
    }
  }
}

// ---------------------------------------------------------------------------
// K3: recheck — fp64 accumulation over fp32 q,k (unchanged from R9).
// ---------------------------------------------------------------------------
__global__ __launch_bounds__(256) void recheck(
    const float* __restrict__ qf, const float* __restrict__ kf,
    const int* __restrict__ cnt, const int* __restrict__ list,
    float* __restrict__ star, int* __restrict__ argb) {
  __shared__ double bvS[4];
  __shared__ int biS[4];
  int n = cnt[0];
  int tid = threadIdx.x;
  int lane = tid & 63, wv = tid >> 6;
  for (int idx = blockIdx.x; idx < n; idx += gridDim.x) {
    int e = list[idx];
    int b = e >> 12, j = e & 4095;
    const float* qp = qf + ((size_t)b * HWn + j) * 32;
    double qj[32];
#pragma unroll
    for (int o = 0; o < 32; ++o) qj[o] = (double)qp[o];
    double best = -1.0e300;
    int bi = 1 << 30;
    for (int i = tid; i < HWn; i += 256) {
      const float* kp = kf + ((size_t)b * HWn + i) * 32;
      double s = 0.0;
#pragma unroll
      for (int o = 0; o < 32; ++o) s += (double)kp[o] * qj[o];
      if (s > best) { best = s; bi = i; }
    }
#pragma unroll
    for (int m = 1; m < 64; m <<= 1) {
      double ob = __shfl_xor(best, m, 64);
      int oi = __shfl_xor(bi, m, 64);
      if (ob > best || (ob == best && oi < bi)) { best = ob; bi = oi; }
    }
    if (lane == 0) { bvS[wv] = best; biS[wv] = bi; }
    __syncthreads();
    if (tid == 0) {
#pragma unroll
      for (int w = 1; w < 4; ++w) {
        if (bvS[w] > best || (bvS[w] == best && biS[w] < bi)) {
          best = bvS[w]; bi = biS[w];
        }
      }
      star[(size_t)b * HWn + j] = (float)best;
      argb[(size_t)b * HWn + j] = bi;
    }
    __syncthreads();
  }
}

// ---------------------------------------------------------------------------
// K4 (R16): transpose to bf16 pixel-major, vectorized.
// float4 loads (dense 256B per 16 lanes) + u16x8 stores (128B chunks).
// Same per-element f2bf and tile mapping as before -> bit-identical output.
// ---------------------------------------------------------------------------
__global__ __launch_bounds__(256) void cat_fx(
    const float* __restrict__ fx, const float* __restrict__ fxh,
    unsigned short* __restrict__ catC, unsigned short* __restrict__ xht) {
  int j0 = blockIdx.x * 64;
  int ci0 = blockIdx.y * 64;
  int b = blockIdx.z >> 1;
  int which = blockIdx.z & 1;
  int tid = threadIdx.x;
  __shared__ unsigned short tile[64][66];

  const float* src = (which == 0) ? fx : fxh;
  // load: 64x64 f32 tile as 1024 float4 (4 iters of 256 threads)
#pragma unroll
  for (int u = tid; u < 1024; u += 256) {
    int cl = u >> 4, h4 = (u & 15) * 4;
    floatx4 v = *reinterpret_cast<const floatx4*>(
        &src[((size_t)(b * Cn + ci0 + cl)) * HWn + j0 + h4]);
#pragma unroll
    for (int k = 0; k < 4; ++k) tile[cl][h4 + k] = f2bf(v[k]);
  }
  __syncthreads();
  // store: 512 u16x8 (2 iters of 256 threads); 8 lanes cover 128B contiguous
#pragma unroll
  for (int u = tid; u < 512; u += 256) {
    int oct = u & 7, hw_l = u >> 3;
    u16x8 val;
#pragma unroll
    for (int k = 0; k < 8; ++k) val[k] = tile[oct * 8 + k][hw_l];
    if (which == 0)
      *reinterpret_cast<u16x8*>(
          &catC[((size_t)b * ROWS + PADR + j0 + hw_l) * 512 + ci0 + oct * 8]) = val;
    else
      *reinterpret_cast<u16x8*>(
          &xht[((size_t)b * HWn + j0 + hw_l) * 256 + ci0 + oct * 8]) = val;
  }
}

// ---------------------------------------------------------------------------
// K5: v projection as bf16 MFMA GEMM, XOR-swizzled LDS (R13 counted-vmcnt).
// ---------------------------------------------------------------------------
__global__ __launch_bounds__(256) void proj_v_mfma(
    const unsigned short* __restrict__ xht, const unsigned short* __restrict__ Wvb,
    const float* __restrict__ bv, unsigned short* __restrict__ vbf) {
  int m0 = blockIdx.x * 128;
  int o0 = blockIdx.y * 128;
  int b = blockIdx.z;
  int tid = threadIdx.x;
  int lane = tid & 63, wv = tid >> 6;
  int wm = wv >> 1, wn = wv & 1;
  int lm = lane & 15, lq = lane >> 4;

  union SMu {
    struct { unsigned short A[2][128 * 32]; unsigned short B[2][128 * 32]; } st;
    unsigned short TS[128 * 136];
  };
  __shared__ __align__(16) SMu sm;

  floatx4 acc[4][4];
#pragma unroll
  for (int im = 0; im < 4; ++im)
#pragma unroll
    for (int in = 0; in < 4; ++in) acc[im][in] = (floatx4)0.0f;

  const int srow = lane >> 2;
  const int soff = (((lane & 3) ^ ((lane >> 3) & 3)) * 8);   // swizzled source chunk
  const int sa = (lq ^ ((lm >> 1) & 3)) * 8;                 // swizzled read column
  const unsigned short* ag = Wvb + (size_t)o0 * 256;
  const unsigned short* bg = xht + ((size_t)b * HWn + m0) * 256;

  auto STAGE = [&](int buf, int kc) {
#pragma unroll
    for (int i = 0; i < 2; ++i) {
      int r0 = wv * 32 + i * 16;
      gl_lds16(ag + ((size_t)(r0 + srow)) * 256 + kc + soff, &sm.st.A[buf][r0 * 32]);
      gl_lds16(bg + ((size_t)(r0 + srow)) * 256 + kc + soff, &sm.st.B[buf][r0 * 32]);
    }
  };
  auto COMPUTE = [&](int buf) {
    bf16x8 afr[4];
#pragma unroll
    for (int im = 0; im < 4; ++im)
      afr[im] = *reinterpret_cast<const bf16x8*>(
          &sm.st.A[buf][(wm * 64 + im * 16 + lm) * 32 + sa]);
#pragma unroll
    for (int in = 0; in < 4; ++in) {
      bf16x8 bfr = *reinterpret_cast<const bf16x8*>(
          &sm.st.B[buf][(wn * 64 + in * 16 + lm) * 32 + sa]);
#pragma unroll
      for (int im = 0; im < 4; ++im)
        acc[im][in] = __builtin_amdgcn_mfma_f32_16x16x32_bf16(
            afr[im], bfr, acc[im][in], 0, 0, 0);
    }
  };

  STAGE(0, 0);
#pragma unroll 2
  for (int st = 0; st < 8; ++st) {
    __builtin_amdgcn_s_barrier();            // buf[(st+1)&1] free to overwrite
    if (st < 7) {
      STAGE((st + 1) & 1, (st + 1) * 32);
      asm volatile("s_waitcnt vmcnt(4)" ::: "memory");   // tile st landed
    } else {
      asm volatile("s_waitcnt vmcnt(0)" ::: "memory");
    }
    __builtin_amdgcn_s_barrier();
    __builtin_amdgcn_sched_barrier(0);
    COMPUTE(st & 1);
  }
  __builtin_amdgcn_s_barrier();   // all waves done reading before TS overwrite

  // epilogue: TS aliases the (now dead) stage buffers.
#pragma unroll
  for (int in = 0; in < 4; ++in) {
    int pl = wn * 64 + in * 16 + lm;
#pragma unroll
    for (int im = 0; im < 4; ++im) {
#pragma unroll
      for (int r = 0; r < 4; ++r) {
        int ol = wm * 64 + im * 16 + lq * 4 + r;
        sm.TS[pl * 136 + ol] = f2bf(acc[im][in][r] + bv[o0 + ol]);
      }
    }
  }
  __syncthreads();
  for (int idx = tid; idx < 128 * 16; idx += 256) {
    int p = idx >> 4, ch = idx & 15;
    u16x8 val = *reinterpret_cast<const u16x8*>(&sm.TS[p * 136 + ch * 8]);
    *reinterpret_cast<u16x8*>(
        &vbf[((size_t)b * HWn + m0 + p) * 256 + o0 + ch * 8]) = val;
  }
}

// ---------------------------------------------------------------------------
// K6: gather (unchanged).
// ---------------------------------------------------------------------------
__global__ __launch_bounds__(256) void gather_cat(
    const unsigned short* __restrict__ vbf, const int* __restrict__ argb,
    unsigned short* __restrict__ catC) {
  int b = blockIdx.y;
  int tid = threadIdx.x;
  if (blockIdx.x == 16) {
    for (int u = tid; u < 2 * PADR * 512; u += 256) {
      int r = u >> 9;
      int rr = (r < PADR) ? r : (HWn + r);
      catC[((size_t)b * ROWS + rr) * 512 + (u & 511)] = 0;
    }
    return;
  }
  __shared__ int ajS[256];
  int j0 = blockIdx.x * 256;
  ajS[tid] = argb[(size_t)b * HWn + j0 + tid];
  __syncthreads();
#pragma unroll 4
  for (int u = tid; u < 256 * 32; u += 256) {
    int pl = u >> 5, ch = u & 31;
    int aj = ajS[pl];
    u16x8 val = *reinterpret_cast<const u16x8*>(
        &vbf[((size_t)b * HWn + aj) * 256 + ch * 8]);
    *reinterpret_cast<u16x8*>(
        &catC[((size_t)b * ROWS + PADR + j0 + pl) * 512 + 256 + ch * 8]) = val;
  }
}

// ---------------------------------------------------------------------------
// K7 (R16 = R11-exact): conv3x3 implicit GEMM, split-K over tap-rows,
// XOR-swizzled LDS, 2-phase double-buffer, bf16 partials. Proven 44.6 us.
// ---------------------------------------------------------------------------
__global__ __launch_bounds__(256) void conv_mfma(
    const unsigned short* __restrict__ catC, const unsigned short* __restrict__ Wfb,
    unsigned short* __restrict__ Pg) {
  int m0 = blockIdx.x * 128;
  int o0 = blockIdx.y * 128;
  int bz = blockIdx.z;
  int b = bz / 3, g = bz % 3;      // g = dy+1
  int dy = g - 1;
  int tid = threadIdx.x;
  int lane = tid & 63;
  int wv = tid >> 6;
  int wm = wv >> 1, wn = wv & 1;
  int lm = lane & 15, lq = lane >> 4;
  const bool lane_first = (lm == 0);
  const bool lane_last = (lm == 15);

  __shared__ __align__(16) unsigned short AS[2][3 * 128 * 32];  // 2x24KB
  __shared__ __align__(16) unsigned short BS[2][144 * 32];      // 2x 9KB

  floatx4 acc[4][4];
#pragma unroll
  for (int im = 0; im < 4; ++im)
#pragma unroll
    for (int in = 0; in < 4; ++in) acc[im][in] = (floatx4)0.0f;

  const int srow = lane >> 2;
  const int soff = (((lane & 3) ^ ((lane >> 3) & 3)) * 8);   // swizzled source chunk
  const int sa = (lq ^ ((lm >> 1) & 3)) * 8;                 // A read column
  const unsigned short* bg =
      catC + ((size_t)b * ROWS + PADR + m0 + dy * 64 - 1) * 512;
  const unsigned short* ag = Wfb + ((size_t)(g * 3) * 256 + o0) * 512;

  auto STAGE = [&](unsigned short* ASb, unsigned short* BSb, int kc) {
    if (wv < 3) {
      const unsigned short* at = ag + (size_t)wv * 256 * 512;
#pragma unroll
      for (int s = 0; s < 8; ++s)
        gl_lds16(at + ((size_t)(s * 16 + srow)) * 512 + kc + soff,
                 &ASb[(wv * 128 + s * 16) * 32]);
    } else {
#pragma unroll
      for (int s = 0; s < 9; ++s)
        gl_lds16(bg + ((size_t)(s * 16 + srow)) * 512 + kc + soff,
                 &BSb[(s * 16) * 32]);
    }
  };
  auto COMPUTE = [&](const unsigned short* ASb, const unsigned short* BSb) {
#pragma unroll
    for (int t = 0; t < 3; ++t) {   // t = dx+1
      bf16x8 afr[4];
#pragma unroll
      for (int im = 0; im < 4; ++im)
        afr[im] = *reinterpret_cast<const bf16x8*>(
            &ASb[(t * 128 + wm * 64 + im * 16 + lm) * 32 + sa]);
#pragma unroll
      for (int in = 0; in < 4; ++in) {
        int u = wn * 64 + in * 16 + lm + t;   // p + 1 + dx
        int sb = (lq ^ ((u >> 1) & 3)) * 8;
        u16x8 braw = *reinterpret_cast<const u16x8*>(&BSb[u * 32 + sb]);
        if ((t == 0 && in == 0 && lane_first) ||
            (t == 2 && in == 3 && lane_last))
          braw = (u16x8)(unsigned short)0;
        union { u16x8 u8; bf16x8 h; } cvt; cvt.u8 = braw;
#pragma unroll
        for (int im = 0; im < 4; ++im)
          acc[im][in] = __builtin_amdgcn_mfma_f32_16x16x32_bf16(
              afr[im], cvt.h, acc[im][in], 0, 0, 0);
      }
    }
  };

  STAGE(AS[0], BS[0], 0);
  __syncthreads();
  for (int kci = 0; kci < 16; kci += 2) {
    if (kci < 15) STAGE(AS[1], BS[1], (kci + 1) * 32);
    COMPUTE(AS[0], BS[0]);
    __syncthreads();
    if (kci < 14) STAGE(AS[0], BS[0], (kci + 2) * 32);
    COMPUTE(AS[1], BS[1]);
    __syncthreads();
  }

  unsigned short* P = Pg + ((size_t)(g * Bn + b) * Cn) * HWn;
#pragma unroll
  for (int in = 0; in < 4; ++in) {
    int p = m0 + wn * 64 + in * 16 + lm;
#pragma unroll
    for (int im = 0; im < 4; ++im) {
      int ob = o0 + wm * 64 + im * 16 + lq * 4;
#pragma unroll
      for (int r = 0; r < 4; ++r)
        P[(size_t)(ob + r) * HWn + p] = f2bf(acc[im][in][r]);
    }
  }
}

// ---------------------------------------------------------------------------
// K8: combine: out = fx + (P0+P1+P2 + bf)*S over bf16 partials, 8 elem/thread.
// ---------------------------------------------------------------------------
__global__ __launch_bounds__(256) void combine(
    const unsigned short* __restrict__ Pg, const float* __restrict__ fx,
    const float* __restrict__ bf, const float* __restrict__ star,
    float* __restrict__ out) {
  size_t e = ((size_t)blockIdx.x * 256 + threadIdx.x) * 8;
  int p = (int)(e & 4095);
  int bo = (int)(e >> 12);
  int o = bo & 255, b = bo >> 8;
  const size_t gs = (size_t)Bn * Cn * HWn;
  u16x8 q0 = *reinterpret_cast<const u16x8*>(Pg + e);
  u16x8 q1 = *reinterpret_cast<const u16x8*>(Pg + gs + e);
  u16x8 q2 = *reinterpret_cast<const u16x8*>(Pg + 2 * gs + e);
  float bias = bf[o];
  const float* sp = star + (size_t)b * HWn + p;
  const float* fp = fx + e;
  float* op = out + e;
#pragma unroll
  for (int h = 0; h < 2; ++h) {
    floatx4 s = *reinterpret_cast<const floatx4*>(sp + h * 4);
    floatx4 f = *reinterpret_cast<const floatx4*>(fp + h * 4);
    floatx4 r;
#pragma unroll
    for (int i = 0; i < 4; ++i) {
      int k = h * 4 + i;
      float a = bf2f(q0[k]) + bf2f(q1[k]) + bf2f(q2[k]);
      r[i] = f[i] + (a + bias) * s[i];
    }
    *reinterpret_cast<floatx4*>(op + h * 4) = r;
  }
}

// ---------------------------------------------------------------------------
extern "C" void kernel_launch(void* const* d_in, const int* in_sizes, int n_in,
                              void* d_out, int out_size, void* d_ws, size_t ws_size,
                              hipStream_t stream) {
  const float* front_x   = (const float*)d_in[0];
  const float* cross_x   = (const float*)d_in[1];
  const float* front_hat = (const float*)d_in[2];
  const float* Wq = (const float*)d_in[3];
  const float* bq = (const float*)d_in[4];
  const float* Wk = (const float*)d_in[5];
  const float* bk = (const float*)d_in[6];
  const float* Wv = (const float*)d_in[7];
  const float* bv = (const float*)d_in[8];
  const float* Wf = (const float*)d_in[9];
  const float* bf = (const float*)d_in[10];
  float* out = (float*)d_out;

  char* ws = (char*)d_ws;
  size_t off = 0;
  auto alloc = [&](size_t bytes) -> void* {
    void* p = (void*)(ws + off);
    off += (bytes + 255) & ~(size_t)255;
    return p;
  };
  float* Wqf = (float*)alloc(8192 * sizeof(float));
  float* Wkf = (float*)alloc(8192 * sizeof(float));
  unsigned short* Wvb = (unsigned short*)alloc(65536 * sizeof(unsigned short));
  unsigned short* Wfb = (unsigned short*)alloc((size_t)9 * 256 * 512 * sizeof(unsigned short));
  float* qf  = (float*)alloc((size_t)Bn * HWn * C8 * sizeof(float));
  float* kf  = (float*)alloc((size_t)Bn * HWn * C8 * sizeof(float));
  unsigned short* qhi = (unsigned short*)alloc((size_t)Bn * HWn * C8 * 2);
  unsigned short* qlo = (unsigned short*)alloc((size_t)Bn * HWn * C8 * 2);
  unsigned short* khi = (unsigned short*)alloc((size_t)Bn * HWn * C8 * 2);
  unsigned short* klo = (unsigned short*)alloc((size_t)Bn * HWn * C8 * 2);
  float*  star = (float*)alloc((size_t)Bn * HWn * sizeof(float));
  int*    argb = (int*)alloc((size_t)Bn * HWn * sizeof(int));
  int*    cnt  = (int*)alloc(256);
  int*    list = (int*)alloc((size_t)Bn * HWn * sizeof(int));
  unsigned short* xht = (unsigned short*)alloc((size_t)Bn * HWn * 256 * 2);
  unsigned short* vbf = (unsigned short*)alloc((size_t)Bn * HWn * 256 * 2);
  unsigned short* catC = (unsigned short*)alloc((size_t)Bn * ROWS * 512 * sizeof(unsigned short));
  unsigned short* Pg = (unsigned short*)alloc((size_t)3 * Bn * Cn * HWn * 2);  // 25 MB bf16

  prep_w<<<dim3((9 * 256 * 512 + 255) / 256), dim3(256), 0, stream>>>(
      Wq, Wk, Wv, Wf, Wqf, Wkf, Wvb, Wfb, cnt);

  proj_qk<<<dim3(HWn / 64, Bn, 2), dim3(1024), 0, stream>>>(
      cross_x, front_x, Wqf, bq, Wkf, bk, qf, kf, qhi, qlo, khi, klo);

  energy_approx<<<dim3(HWn / 32, Bn), dim3(1024), 0, stream>>>(
      khi, klo, qhi, qlo, star, argb, cnt, list);

  recheck<<<dim3(256), dim3(256), 0, stream>>>(qf, kf, cnt, list, star, argb);

  cat_fx<<<dim3(HWn / 64, Cn / 64, Bn * 2), dim3(256), 0, stream>>>(
      front_x, front_hat, catC, xht);

  proj_v_mfma<<<dim3(HWn / 128, Cn / 128, Bn), dim3(256), 0, stream>>>(
      xht, Wvb, bv, vbf);

  gather_cat<<<dim3(HWn / 256 + 1, Bn), dim3(256), 0, stream>>>(vbf, argb, catC);

  conv_mfma<<<dim3(HWn / 128, Cn / 128, Bn * 3), dim3(256), 0, stream>>>(
      catC, Wfb, Pg);

  combine<<<dim3((Bn * Cn * HWn / 8) / 256), dim3(256), 0, stream>>>(
      Pg, front_x, bf, star, out);
}

// Round 8
// 238.532 us; speedup vs baseline: 1.6333x; 1.0099x over previous
//
#include <hip/hip_runtime.h>

#define Bn 4
#define Cn 256
#define C8 32
#define Hn 64
#define Wn 64
#define HWn 4096
#define PADR 80
#define ROWS (HWn + 2 * PADR)   // 4256 padded pixel-rows per batch
#define MARGIN 6e-3f

typedef __bf16 bf16x8 __attribute__((ext_vector_type(8)));
typedef float floatx4 __attribute__((ext_vector_type(4)));
typedef unsigned short u16x8 __attribute__((ext_vector_type(8)));

__device__ __forceinline__ unsigned short f2bf(float f) {
  union { float f; unsigned int u; } c; c.f = f;
  unsigned int u = c.u;
  return (unsigned short)((u + 0x7FFFu + ((u >> 16) & 1u)) >> 16);  // RNE
}
__device__ __forceinline__ float bf2f(unsigned short h) {
  union { unsigned int u; float f; } c; c.u = ((unsigned int)h) << 16;
  return c.f;
}
__device__ __forceinline__ void gl_lds16(const void* g, void* l) {
  __builtin_amdgcn_global_load_lds(
      (__attribute__((address_space(1))) void*)(uintptr_t)g,
      (__attribute__((address_space(3))) void*)(uintptr_t)l, 16, 0, 0);
}

// ---------------------------------------------------------------------------
// K0: weight prep + zero flagged-query counter (unchanged).
// ---------------------------------------------------------------------------
__global__ void prep_w(const float* __restrict__ Wq, const float* __restrict__ Wk,
                       const float* __restrict__ Wv, const float* __restrict__ Wf,
                       float* __restrict__ Wqf, float* __restrict__ Wkf,
                       unsigned short* __restrict__ Wvb, unsigned short* __restrict__ Wfb,
                       int* __restrict__ cnt) {
  size_t t = (size_t)blockIdx.x * 256 + threadIdx.x;
  if (t == 0) cnt[0] = 0;
  if (t < 8192) {
    int o = (int)(t / 256), c = (int)(t % 256);
    Wqf[(size_t)c * 32 + o] = Wq[t];
    Wkf[(size_t)c * 32 + o] = Wk[t];
  }
  if (t < 65536) Wvb[t] = f2bf(Wv[t]);   // [o][c] row-major already
  if (t < (size_t)9 * 256 * 512) {
    int tap = (int)(t / (256 * 512));
    int rem = (int)(t % (256 * 512));
    int o = rem / 512, ci = rem % 512;
    Wfb[t] = f2bf(Wf[((size_t)o * 512 + ci) * 9 + tap]);
  }
}

// ---------------------------------------------------------------------------
// K1: q/k projection in FP32 (unchanged from R9).
// ---------------------------------------------------------------------------
__global__ __launch_bounds__(1024) void proj_qk(
    const float* __restrict__ cross_x, const float* __restrict__ front_x,
    const float* __restrict__ Wqf, const float* __restrict__ bq,
    const float* __restrict__ Wkf, const float* __restrict__ bk,
    float* __restrict__ qf, float* __restrict__ kf,
    unsigned short* __restrict__ qhi, unsigned short* __restrict__ qlo,
    unsigned short* __restrict__ khi, unsigned short* __restrict__ klo) {
  int tid = threadIdx.x;
  int lane = tid & 63, wv = tid >> 6;    // 16 waves
  int slice = wv & 3;                    // o-slice (8 o each)
  int chunk = wv >> 2;                   // c-chunk (64 c each)
  int j = blockIdx.x * 64 + lane;
  int b = blockIdx.y;
  int z = blockIdx.z;
  const float* x = (z == 0) ? cross_x : front_x;
  const float* Wg = (z == 0) ? Wqf : Wkf;
  const float* bd = (z == 0) ? bq : bk;
  float* outp = (z == 0) ? qf : kf;
  unsigned short* hip_ = (z == 0) ? qhi : khi;
  unsigned short* lop_ = (z == 0) ? qlo : klo;
  int o0 = slice * 8;
  int c0 = chunk * 64;

  __shared__ __align__(16) float Wl[8192];        // [c][32] fp32, 32KB
  __shared__ float part[3 * 4 * 8 * 64];          // [chunk-1][slice][o][lane] 24KB

  for (int u = tid; u < 8192; u += 1024) Wl[u] = Wg[u];
  __syncthreads();

  const float* xb = x + (size_t)b * Cn * HWn + j;
  floatx4 a0 = (floatx4)0.0f, a1 = (floatx4)0.0f;
#pragma unroll 16
  for (int c = c0; c < c0 + 64; ++c) {
    float xv = xb[(size_t)c * HWn];
    floatx4 wa = *reinterpret_cast<const floatx4*>(&Wl[c * 32 + o0]);      // broadcast
    floatx4 wb = *reinterpret_cast<const floatx4*>(&Wl[c * 32 + o0 + 4]);
    a0 += wa * xv;
    a1 += wb * xv;
  }
  if (chunk > 0) {
    float* dst = &part[(((chunk - 1) * 4 + slice) * 8) * 64];
#pragma unroll
    for (int o = 0; o < 4; ++o) { dst[o * 64 + lane] = a0[o]; dst[(o + 4) * 64 + lane] = a1[o]; }
  }
  __syncthreads();
  if (chunk != 0) return;
#pragma unroll
  for (int q = 0; q < 3; ++q) {
    const float* src = &part[((q * 4 + slice) * 8) * 64];
#pragma unroll
    for (int o = 0; o < 4; ++o) { a0[o] += src[o * 64 + lane]; a1[o] += src[(o + 4) * 64 + lane]; }
  }
  float acc[8];
#pragma unroll
  for (int o = 0; o < 4; ++o) { acc[o] = a0[o] + bd[o0 + o]; acc[o + 4] = a1[o] + bd[o0 + 4 + o]; }

  float* op = outp + ((size_t)b * HWn + j) * C8 + o0;
  u16x8 hv, lv;
#pragma unroll
  for (int o = 0; o < 8; ++o) {
    op[o] = acc[o];
    unsigned short h = f2bf(acc[o]);
    hv[o] = h;
    lv[o] = f2bf(acc[o] - bf2f(h));
  }
  *reinterpret_cast<u16x8*>(hip_ + ((size_t)b * HWn + j) * C8 + o0) = hv;
  *reinterpret_cast<u16x8*>(lop_ + ((size_t)b * HWn + j) * C8 + o0) = lv;
}

// ---------------------------------------------------------------------------
// K2 (R17): energy_approx CO-LAUNCHED with cat_fx in one grid.
// Even blockIdx -> energy (R10 body, byte-identical); odd -> cat_fx (R16
// body at 4 ci-tiles per 1024-thread block). Interleaving mixes the
// VALU/MFMA-heavy energy blocks with memory-heavy cat blocks on each CU.
// ---------------------------------------------------------------------------
__global__ __launch_bounds__(1024, 8) void energy_cat(
    const unsigned short* __restrict__ khi, const unsigned short* __restrict__ klo,
    const unsigned short* __restrict__ qhi, const unsigned short* __restrict__ qlo,
    float* __restrict__ star, int* __restrict__ argb,
    int* __restrict__ cnt, int* __restrict__ list,
    const float* __restrict__ fx, const float* __restrict__ fxh,
    unsigned short* __restrict__ catC, unsigned short* __restrict__ xht) {
  int bx = blockIdx.x;
  if ((bx & 1) == 0) {
    // ================= energy path: id 0..511 =================
    int id = bx >> 1;
    int b = id >> 7;
    int j0 = (id & 127) * 32;
    int tid = threadIdx.x;
    int lane = tid & 63, wv = tid >> 6;   // wv 0..15
    int lm = lane & 15, lq = lane >> 4;

    __shared__ float bv1S[16][32];
    __shared__ int   bi1S[16][32];
    __shared__ float bv2S[16][32];

    bf16x8 qh[2], ql[2];
#pragma unroll
    for (int s = 0; s < 2; ++s) {
      int j = j0 + s * 16 + lm;
      qh[s] = *reinterpret_cast<const bf16x8*>(qhi + ((size_t)b * HWn + j) * 32 + lq * 8);
      ql[s] = *reinterpret_cast<const bf16x8*>(qlo + ((size_t)b * HWn + j) * 32 + lq * 8);
    }
    const unsigned short* kh_base = khi + (size_t)b * HWn * 32 + lq * 8;
    const unsigned short* kl_base = klo + (size_t)b * HWn * 32 + lq * 8;

    float b1[2], b2[2];
#pragma unroll
    for (int s = 0; s < 2; ++s) { b1[s] = -3.0e38f; b2[s] = -3.0e38f; }

    int ibase = wv * 256;
#pragma unroll 4
    for (int it = 0; it < 16; ++it) {
      int i0 = ibase + it * 16;
      bf16x8 ah = *reinterpret_cast<const bf16x8*>(kh_base + (size_t)(i0 + lm) * 32);
      bf16x8 al = *reinterpret_cast<const bf16x8*>(kl_base + (size_t)(i0 + lm) * 32);
#pragma unroll
      for (int s = 0; s < 2; ++s) {
        floatx4 acc = (floatx4)0.0f;
        acc = __builtin_amdgcn_mfma_f32_16x16x32_bf16(ah, qh[s], acc, 0, 0, 0);
        acc = __builtin_amdgcn_mfma_f32_16x16x32_bf16(ah, ql[s], acc, 0, 0, 0);
        acc = __builtin_amdgcn_mfma_f32_16x16x32_bf16(al, qh[s], acc, 0, 0, 0);
#pragma unroll
        for (int r = 0; r < 4; ++r) {
          unsigned code = (unsigned)(it * 4 + r);   // SGPR-uniform per (it,r)
          union { float f; unsigned u; } cv; cv.f = acc[r];
          cv.u = (cv.u & ~63u) | code;              // v_and_or_b32
          float vp = cv.f;
          b2[s] = __builtin_amdgcn_fmed3f(vp, b1[s], b2[s]);
          b1[s] = fmaxf(b1[s], vp);
        }
      }
    }
    int i1[2];
#pragma unroll
    for (int s = 0; s < 2; ++s) {
      union { float f; unsigned u; } cv; cv.f = b1[s];
      unsigned code = cv.u & 63u;                   // (it<<2)|r of the winner
      i1[s] = ibase + (int)(code >> 2) * 16 + lq * 4 + (int)(code & 3u);
    }
#pragma unroll
    for (int s = 0; s < 2; ++s) {
#pragma unroll
      for (int m = 16; m <= 32; m <<= 1) {
        float ob1 = __shfl_xor(b1[s], m, 64);
        int oi1 = __shfl_xor(i1[s], m, 64);
        float ob2 = __shfl_xor(b2[s], m, 64);
        float c2;
        if (ob1 > b1[s] || (ob1 == b1[s] && oi1 < i1[s])) {
          c2 = fmaxf(b1[s], ob2);
          b1[s] = ob1; i1[s] = oi1;
        } else {
          c2 = fmaxf(ob1, b2[s]);
        }
        b2[s] = c2;
      }
      if (lq == 0) {
        bv1S[wv][s * 16 + lm] = b1[s];
        bi1S[wv][s * 16 + lm] = i1[s];
        bv2S[wv][s * 16 + lm] = b2[s];
      }
    }
    __syncthreads();
    if (tid < 32) {
      float B1 = bv1S[0][tid];
      int I1 = bi1S[0][tid];
      float B2 = bv2S[0][tid];
#pragma unroll
      for (int w = 1; w < 16; ++w) {
        float v1 = bv1S[w][tid];
        int ii = bi1S[w][tid];
        float v2 = bv2S[w][tid];
        if (v1 > B1) { B2 = fmaxf(B1, v2); B1 = v1; I1 = ii; }
        else B2 = fmaxf(B2, v1);
      }
      size_t o = (size_t)b * HWn + j0 + tid;
      union { float f; unsigned u; } cs; cs.f = B1;
      cs.u &= ~63u;                                 // strip packed index bits
      star[o] = cs.f;
      argb[o] = I1;
      if (B1 - B2 < MARGIN) {
        int slot = atomicAdd(cnt, 1);
        list[slot] = (b << 12) | (j0 + (int)tid);
      }
    }
  } else {
    // ================= cat path: id 0..511 =================
    int id = bx >> 1;
    int j0 = (id & 63) * 64;
    int bz = id >> 6;                  // 0..7
    int b = bz >> 1, which = bz & 1;
    int g4 = threadIdx.x >> 8;         // 4 groups of 256 threads
    int tid = threadIdx.x & 255;
    int ci0 = g4 * 64;
    __shared__ unsigned short tile[4][64][66];

    const float* src = (which == 0) ? fx : fxh;
#pragma unroll
    for (int u = tid; u < 1024; u += 256) {
      int cl = u >> 4, h4 = (u & 15) * 4;
      floatx4 v = *reinterpret_cast<const floatx4*>(
          &src[((size_t)(b * Cn + ci0 + cl)) * HWn + j0 + h4]);
#pragma unroll
      for (int k = 0; k < 4; ++k) tile[g4][cl][h4 + k] = f2bf(v[k]);
    }
    __syncthreads();
#pragma unroll
    for (int u = tid; u < 512; u += 256) {
      int oct = u & 7, hw_l = u >> 3;
      u16x8 val;
#pragma unroll
      for (int k = 0; k < 8; ++k) val[k] = tile[g4][oct * 8 + k][hw_l];
      if (which == 0)
        *reinterpret_cast<u16x8*>(
            &catC[((size_t)b * ROWS + PADR + j0 + hw_l) * 512 + ci0 + oct * 8]) = val;
      else
        *reinterpret_cast<u16x8*>(
            &xht[((size_t)b * HWn + j0 + hw_l) * 256 + ci0 + oct * 8]) = val;
    }
  }
}

// ---------------------------------------------------------------------------
// K3 (R17): recheck CO-LAUNCHED with proj_v_mfma (both 256-thread blocks,
// interleaved even/odd; all 512 blocks co-resident at 4 blocks/CU).
// ---------------------------------------------------------------------------
__global__ __launch_bounds__(256) void recheck_projv(
    const unsigned short* __restrict__ xht, const unsigned short* __restrict__ Wvb,
    const float* __restrict__ bv, unsigned short* __restrict__ vbf,
    const float* __restrict__ qf, const float* __restrict__ kf,
    const int* __restrict__ cnt, const int* __restrict__ list,
    float* __restrict__ star, int* __restrict__ argb) {
  int bx = blockIdx.x;
  if ((bx & 1) == 0) {
    // ================= proj_v path: id 0..255 =================
    int id = bx >> 1;
    int m0 = (id & 31) * 128;
    int o0 = ((id >> 5) & 1) * 128;
    int b = id >> 6;
    int tid = threadIdx.x;
    int lane = tid & 63, wv = tid >> 6;
    int wm = wv >> 1, wn = wv & 1;
    int lm = lane & 15, lq = lane >> 4;

    union SMu {
      struct { unsigned short A[2][128 * 32]; unsigned short B[2][128 * 32]; } st;
      unsigned short TS[128 * 136];
    };
    __shared__ __align__(16) SMu sm;

    floatx4 acc[4][4];
#pragma unroll
    for (int im = 0; im < 4; ++im)
#pragma unroll
      for (int in = 0; in < 4; ++in) acc[im][in] = (floatx4)0.0f;

    const int srow = lane >> 2;
    const int soff = (((lane & 3) ^ ((lane >> 3) & 3)) * 8);   // swizzled source chunk
    const int sa = (lq ^ ((lm >> 1) & 3)) * 8;                 // swizzled read column
    const unsigned short* ag = Wvb + (size_t)o0 * 256;
    const unsigned short* bg = xht + ((size_t)b * HWn + m0) * 256;

    auto STAGE = [&](int buf, int kc) {
#pragma unroll
      for (int i = 0; i < 2; ++i) {
        int r0 = wv * 32 + i * 16;
        gl_lds16(ag + ((size_t)(r0 + srow)) * 256 + kc + soff, &sm.st.A[buf][r0 * 32]);
        gl_lds16(bg + ((size_t)(r0 + srow)) * 256 + kc + soff, &sm.st.B[buf][r0 * 32]);
      }
    };
    auto COMPUTE = [&](int buf) {
      bf16x8 afr[4];
#pragma unroll
      for (int im = 0; im < 4; ++im)
        afr[im] = *reinterpret_cast<const bf16x8*>(
            &sm.st.A[buf][(wm * 64 + im * 16 + lm) * 32 + sa]);
#pragma unroll
      for (int in = 0; in < 4; ++in) {
        bf16x8 bfr = *reinterpret_cast<const bf16x8*>(
            &sm.st.B[buf][(wn * 64 + in * 16 + lm) * 32 + sa]);
#pragma unroll
        for (int im = 0; im < 4; ++im)
          acc[im][in] = __builtin_amdgcn_mfma_f32_16x16x32_bf16(
              afr[im], bfr, acc[im][in], 0, 0, 0);
      }
    };

    STAGE(0, 0);
#pragma unroll 2
    for (int st = 0; st < 8; ++st) {
      __builtin_amdgcn_s_barrier();            // buf[(st+1)&1] free to overwrite
      if (st < 7) {
        STAGE((st + 1) & 1, (st + 1) * 32);
        asm volatile("s_waitcnt vmcnt(4)" ::: "memory");   // tile st landed
      } else {
        asm volatile("s_waitcnt vmcnt(0)" ::: "memory");
      }
      __builtin_amdgcn_s_barrier();
      __builtin_amdgcn_sched_barrier(0);
      COMPUTE(st & 1);
    }
    __builtin_amdgcn_s_barrier();   // all waves done reading before TS overwrite

    // epilogue: TS aliases the (now dead) stage buffers.
#pragma unroll
    for (int in = 0; in < 4; ++in) {
      int pl = wn * 64 + in * 16 + lm;
#pragma unroll
      for (int im = 0; im < 4; ++im) {
#pragma unroll
        for (int r = 0; r < 4; ++r) {
          int ol = wm * 64 + im * 16 + lq * 4 + r;
          sm.TS[pl * 136 + ol] = f2bf(acc[im][in][r] + bv[o0 + ol]);
        }
      }
    }
    __syncthreads();
    for (int idx = tid; idx < 128 * 16; idx += 256) {
      int p = idx >> 4, ch = idx & 15;
      u16x8 val = *reinterpret_cast<const u16x8*>(&sm.TS[p * 136 + ch * 8]);
      *reinterpret_cast<u16x8*>(
          &vbf[((size_t)b * HWn + m0 + p) * 256 + o0 + ch * 8]) = val;
    }
  } else {
    // ================= recheck path: stride 256 over list =================
    __shared__ double bvS[4];
    __shared__ int biS[4];
    int n = cnt[0];
    int tid = threadIdx.x;
    int lane = tid & 63, wv = tid >> 6;
    for (int idx = bx >> 1; idx < n; idx += 256) {
      int e = list[idx];
      int b = e >> 12, j = e & 4095;
      const float* qp = qf + ((size_t)b * HWn + j) * 32;
      double qj[32];
#pragma unroll
      for (int o = 0; o < 32; ++o) qj[o] = (double)qp[o];
      double best = -1.0e300;
      int bi = 1 << 30;
      for (int i = tid; i < HWn; i += 256) {
        const float* kp = kf + ((size_t)b * HWn + i) * 32;
        double s = 0.0;
#pragma unroll
        for (int o = 0; o < 32; ++o) s += (double)kp[o] * qj[o];
        if (s > best) { best = s; bi = i; }
      }
#pragma unroll
      for (int m = 1; m < 64; m <<= 1) {
        double ob = __shfl_xor(best, m, 64);
        int oi = __shfl_xor(bi, m, 64);
        if (ob > best || (ob == best && oi < bi)) { best = ob; bi = oi; }
      }
      if (lane == 0) { bvS[wv] = best; biS[wv] = bi; }
      __syncthreads();
      if (tid == 0) {
#pragma unroll
        for (int w = 1; w < 4; ++w) {
          if (bvS[w] > best || (bvS[w] == best && biS[w] < bi)) {
            best = bvS[w]; bi = biS[w];
          }
        }
        star[(size_t)b * HWn + j] = (float)best;
        argb[(size_t)b * HWn + j] = bi;
      }
      __syncthreads();
    }
  }
}

// ---------------------------------------------------------------------------
// K6: gather (unchanged).
// ---------------------------------------------------------------------------
__global__ __launch_bounds__(256) void gather_cat(
    const unsigned short* __restrict__ vbf, const int* __restrict__ argb,
    unsigned short* __restrict__ catC) {
  int b = blockIdx.y;
  int tid = threadIdx.x;
  if (blockIdx.x == 16) {
    for (int u = tid; u < 2 * PADR * 512; u += 256) {
      int r = u >> 9;
      int rr = (r < PADR) ? r : (HWn + r);
      catC[((size_t)b * ROWS + rr) * 512 + (u & 511)] = 0;
    }
    return;
  }
  __shared__ int ajS[256];
  int j0 = blockIdx.x * 256;
  ajS[tid] = argb[(size_t)b * HWn + j0 + tid];
  __syncthreads();
#pragma unroll 4
  for (int u = tid; u < 256 * 32; u += 256) {
    int pl = u >> 5, ch = u & 31;
    int aj = ajS[pl];
    u16x8 val = *reinterpret_cast<const u16x8*>(
        &vbf[((size_t)b * HWn + aj) * 256 + ch * 8]);
    *reinterpret_cast<u16x8*>(
        &catC[((size_t)b * ROWS + PADR + j0 + pl) * 512 + 256 + ch * 8]) = val;
  }
}

// ---------------------------------------------------------------------------
// K7 (R11-exact): conv3x3 implicit GEMM, split-K over tap-rows,
// XOR-swizzled LDS, 2-phase double-buffer, bf16 partials. Proven ~45-47 us.
// ---------------------------------------------------------------------------
__global__ __launch_bounds__(256) void conv_mfma(
    const unsigned short* __restrict__ catC, const unsigned short* __restrict__ Wfb,
    unsigned short* __restrict__ Pg) {
  int m0 = blockIdx.x * 128;
  int o0 = blockIdx.y * 128;
  int bz = blockIdx.z;
  int b = bz / 3, g = bz % 3;      // g = dy+1
  int dy = g - 1;
  int tid = threadIdx.x;
  int lane = tid & 63;
  int wv = tid >> 6;
  int wm = wv >> 1, wn = wv & 1;
  int lm = lane & 15, lq = lane >> 4;
  const bool lane_first = (lm == 0);
  const bool lane_last = (lm == 15);

  __shared__ __align__(16) unsigned short AS[2][3 * 128 * 32];  // 2x24KB
  __shared__ __align__(16) unsigned short BS[2][144 * 32];      // 2x 9KB

  floatx4 acc[4][4];
#pragma unroll
  for (int im = 0; im < 4; ++im)
#pragma unroll
    for (int in = 0; in < 4; ++in) acc[im][in] = (floatx4)0.0f;

  const int srow = lane >> 2;
  const int soff = (((lane & 3) ^ ((lane >> 3) & 3)) * 8);   // swizzled source chunk
  const int sa = (lq ^ ((lm >> 1) & 3)) * 8;                 // A read column
  const unsigned short* bg =
      catC + ((size_t)b * ROWS + PADR + m0 + dy * 64 - 1) * 512;
  const unsigned short* ag = Wfb + ((size_t)(g * 3) * 256 + o0) * 512;

  auto STAGE = [&](unsigned short* ASb, unsigned short* BSb, int kc) {
    if (wv < 3) {
      const unsigned short* at = ag + (size_t)wv * 256 * 512;
#pragma unroll
      for (int s = 0; s < 8; ++s)
        gl_lds16(at + ((size_t)(s * 16 + srow)) * 512 + kc + soff,
                 &ASb[(wv * 128 + s * 16) * 32]);
    } else {
#pragma unroll
      for (int s = 0; s < 9; ++s)
        gl_lds16(bg + ((size_t)(s * 16 + srow)) * 512 + kc + soff,
                 &BSb[(s * 16) * 32]);
    }
  };
  auto COMPUTE = [&](const unsigned short* ASb, const unsigned short* BSb) {
#pragma unroll
    for (int t = 0; t < 3; ++t) {   // t = dx+1
      bf16x8 afr[4];
#pragma unroll
      for (int im = 0; im < 4; ++im)
        afr[im] = *reinterpret_cast<const bf16x8*>(
            &ASb[(t * 128 + wm * 64 + im * 16 + lm) * 32 + sa]);
#pragma unroll
      for (int in = 0; in < 4; ++in) {
        int u = wn * 64 + in * 16 + lm + t;   // p + 1 + dx
        int sb = (lq ^ ((u >> 1) & 3)) * 8;
        u16x8 braw = *reinterpret_cast<const u16x8*>(&BSb[u * 32 + sb]);
        if ((t == 0 && in == 0 && lane_first) ||
            (t == 2 && in == 3 && lane_last))
          braw = (u16x8)(unsigned short)0;
        union { u16x8 u8; bf16x8 h; } cvt; cvt.u8 = braw;
#pragma unroll
        for (int im = 0; im < 4; ++im)
          acc[im][in] = __builtin_amdgcn_mfma_f32_16x16x32_bf16(
              afr[im], cvt.h, acc[im][in], 0, 0, 0);
      }
    }
  };

  STAGE(AS[0], BS[0], 0);
  __syncthreads();
  for (int kci = 0; kci < 16; kci += 2) {
    if (kci < 15) STAGE(AS[1], BS[1], (kci + 1) * 32);
    COMPUTE(AS[0], BS[0]);
    __syncthreads();
    if (kci < 14) STAGE(AS[0], BS[0], (kci + 2) * 32);
    COMPUTE(AS[1], BS[1]);
    __syncthreads();
  }

  unsigned short* P = Pg + ((size_t)(g * Bn + b) * Cn) * HWn;
#pragma unroll
  for (int in = 0; in < 4; ++in) {
    int p = m0 + wn * 64 + in * 16 + lm;
#pragma unroll
    for (int im = 0; im < 4; ++im) {
      int ob = o0 + wm * 64 + im * 16 + lq * 4;
#pragma unroll
      for (int r = 0; r < 4; ++r)
        P[(size_t)(ob + r) * HWn + p] = f2bf(acc[im][in][r]);
    }
  }
}

// ---------------------------------------------------------------------------
// K8: combine: out = fx + (P0+P1+P2 + bf)*S over bf16 partials, 8 elem/thread.
// ---------------------------------------------------------------------------
__global__ __launch_bounds__(256) void combine(
    const unsigned short* __restrict__ Pg, const float* __restrict__ fx,
    const float* __restrict__ bf, const float* __restrict__ star,
    float* __restrict__ out) {
  size_t e = ((size_t)blockIdx.x * 256 + threadIdx.x) * 8;
  int p = (int)(e & 4095);
  int bo = (int)(e >> 12);
  int o = bo & 255, b = bo >> 8;
  const size_t gs = (size_t)Bn * Cn * HWn;
  u16x8 q0 = *reinterpret_cast<const u16x8*>(Pg + e);
  u16x8 q1 = *reinterpret_cast<const u16x8*>(Pg + gs + e);
  u16x8 q2 = *reinterpret_cast<const u16x8*>(Pg + 2 * gs + e);
  float bias = bf[o];
  const float* sp = star + (size_t)b * HWn + p;
  const float* fp = fx + e;
  float* op = out + e;
#pragma unroll
  for (int h = 0; h < 2; ++h) {
    floatx4 s = *reinterpret_cast<const floatx4*>(sp + h * 4);
    floatx4 f = *reinterpret_cast<const floatx4*>(fp + h * 4);
    floatx4 r;
#pragma unroll
    for (int i = 0; i < 4; ++i) {
      int k = h * 4 + i;
      float a = bf2f(q0[k]) + bf2f(q1[k]) + bf2f(q2[k]);
      r[i] = f[i] + (a + bias) * s[i];
    }
    *reinterpret_cast<floatx4*>(op + h * 4) = r;
  }
}

// ---------------------------------------------------------------------------
extern "C" void kernel_launch(void* const* d_in, const int* in_sizes, int n_in,
                              void* d_out, int out_size, void* d_ws, size_t ws_size,
                              hipStream_t stream) {
  const float* front_x   = (const float*)d_in[0];
  const float* cross_x   = (const float*)d_in[1];
  const float* front_hat = (const float*)d_in[2];
  const float* Wq = (const float*)d_in[3];
  const float* bq = (const float*)d_in[4];
  const float* Wk = (const float*)d_in[5];
  const float* bk = (const float*)d_in[6];
  const float* Wv = (const float*)d_in[7];
  const float* bv = (const float*)d_in[8];
  const float* Wf = (const float*)d_in[9];
  const float* bf = (const float*)d_in[10];
  float* out = (float*)d_out;

  char* ws = (char*)d_ws;
  size_t off = 0;
  auto alloc = [&](size_t bytes) -> void* {
    void* p = (void*)(ws + off);
    off += (bytes + 255) & ~(size_t)255;
    return p;
  };
  float* Wqf = (float*)alloc(8192 * sizeof(float));
  float* Wkf = (float*)alloc(8192 * sizeof(float));
  unsigned short* Wvb = (unsigned short*)alloc(65536 * sizeof(unsigned short));
  unsigned short* Wfb = (unsigned short*)alloc((size_t)9 * 256 * 512 * sizeof(unsigned short));
  float* qf  = (float*)alloc((size_t)Bn * HWn * C8 * sizeof(float));
  float* kf  = (float*)alloc((size_t)Bn * HWn * C8 * sizeof(float));
  unsigned short* qhi = (unsigned short*)alloc((size_t)Bn * HWn * C8 * 2);
  unsigned short* qlo = (unsigned short*)alloc((size_t)Bn * HWn * C8 * 2);
  unsigned short* khi = (unsigned short*)alloc((size_t)Bn * HWn * C8 * 2);
  unsigned short* klo = (unsigned short*)alloc((size_t)Bn * HWn * C8 * 2);
  float*  star = (float*)alloc((size_t)Bn * HWn * sizeof(float));
  int*    argb = (int*)alloc((size_t)Bn * HWn * sizeof(int));
  int*    cnt  = (int*)alloc(256);
  int*    list = (int*)alloc((size_t)Bn * HWn * sizeof(int));
  unsigned short* xht = (unsigned short*)alloc((size_t)Bn * HWn * 256 * 2);
  unsigned short* vbf = (unsigned short*)alloc((size_t)Bn * HWn * 256 * 2);
  unsigned short* catC = (unsigned short*)alloc((size_t)Bn * ROWS * 512 * sizeof(unsigned short));
  unsigned short* Pg = (unsigned short*)alloc((size_t)3 * Bn * Cn * HWn * 2);  // 25 MB bf16

  prep_w<<<dim3((9 * 256 * 512 + 255) / 256), dim3(256), 0, stream>>>(
      Wq, Wk, Wv, Wf, Wqf, Wkf, Wvb, Wfb, cnt);

  proj_qk<<<dim3(HWn / 64, Bn, 2), dim3(1024), 0, stream>>>(
      cross_x, front_x, Wqf, bq, Wkf, bk, qf, kf, qhi, qlo, khi, klo);

  energy_cat<<<dim3(1024), dim3(1024), 0, stream>>>(
      khi, klo, qhi, qlo, star, argb, cnt, list,
      front_x, front_hat, catC, xht);

  recheck_projv<<<dim3(512), dim3(256), 0, stream>>>(
      xht, Wvb, bv, vbf, qf, kf, cnt, list, star, argb);

  gather_cat<<<dim3(HWn / 256 + 1, Bn), dim3(256), 0, stream>>>(vbf, argb, catC);

  conv_mfma<<<dim3(HWn / 128, Cn / 128, Bn * 3), dim3(256), 0, stream>>>(
      catC, Wfb, Pg);

  combine<<<dim3((Bn * Cn * HWn / 8) / 256), dim3(256), 0, stream>>>(
      Pg, front_x, bf, star, out);
}